// Round 13
// baseline (228.437 us; speedup 1.0000x reference)
//
#include <hip/hip_runtime.h>
#include <hip/hip_bf16.h>

#define BB 16
#define NN 1024
#define CS 256
#define CX 64
#define CC 320
#define PH 64
#define GH 128
#define ELLW 64
#define NENG 7812    // 8-neigh edges per image (H=W=32)
#define ROWP 324     // padded kp row stride in floats (320 + 4)

typedef __hip_bfloat16 bf16;
typedef __attribute__((ext_vector_type(8))) __bf16 bfrag;   // 8 bf16 = 4 VGPRs
typedef __attribute__((ext_vector_type(4))) float v4f;

// ---------------- prep: pack W1 + gc1_w (hi/lo split) into B-frag order --
__global__ __launch_bounds__(256) void k_prep(
    const float* __restrict__ w1, const float* __restrict__ gc1w,
    __bf16* __restrict__ whi, __bf16* __restrict__ wlo,
    __bf16* __restrict__ gwhi, __bf16* __restrict__ gwlo,
    int* __restrict__ cnt, float* __restrict__ Ssum, float* __restrict__ S2sum)
{
    int idx = blockIdx.x * 256 + threadIdx.x;
    if (idx < 10 * 4 * 64 * 8) {          // W1: PH=64 -> 4 ntiles
        int j    = idx & 7;
        int lane = (idx >> 3) & 63;
        int nt   = (idx >> 9) & 3;
        int ks   = idx >> 11;
        int k = ks * 32 + (lane >> 4) * 8 + j;
        int n = nt * 16 + (lane & 15);
        float w = w1[k * PH + n];
        __bf16 h = (__bf16)w;
        whi[idx] = h;
        wlo[idx] = (__bf16)(w - (float)h);
    }
    if (idx < 10 * 8 * 64 * 8) {          // gc1_w: GH=128 -> 8 ntiles
        int j    = idx & 7;
        int lane = (idx >> 3) & 63;
        int nt   = (idx >> 9) & 7;
        int ks   = idx >> 12;
        int k = ks * 32 + (lane >> 4) * 8 + j;
        int n = nt * 16 + (lane & 15);
        float w = gc1w[k * GH + n];
        __bf16 h = (__bf16)w;
        gwhi[idx] = h;
        gwlo[idx] = (__bf16)(w - (float)h);
    }
    if (idx < BB * NN) cnt[idx] = 0;
    if (idx < BB * PH) { Ssum[idx] = 0.f; S2sum[idx] = 0.f; }
}

// ---------------- transpose: [B,C,N] -> featT [B,N,C] f32 ----------------
__global__ __launch_bounds__(256) void k_transpose(
    const float* __restrict__ search, const float* __restrict__ xcorr,
    float* __restrict__ featT)
{
    __shared__ float tile[32][33];
    int blk = blockIdx.x;
    int b   = blk % BB;
    int rem = blk / BB;       // 0..319
    int ct  = rem >> 5;       // 10 channel tiles
    int ntl = rem & 31;       // 32 node tiles
    int tid = threadIdx.x;
    int cl = tid >> 5, nl = tid & 31;
    const float* sb = search + (size_t)b * CS * NN;
    const float* xb = xcorr + (size_t)b * CX * NN;
    #pragma unroll
    for (int f = 0; f < 4; ++f) {
        int c = ct * 32 + cl + f * 8;
        int n = ntl * 32 + nl;
        float v = (c < CS) ? sb[(size_t)c * NN + n] : xb[(size_t)(c - CS) * NN + n];
        tile[cl + f * 8][nl] = v;
    }
    __syncthreads();
    #pragma unroll
    for (int f = 0; f < 4; ++f) {
        int nr = cl + f * 8;
        int cc = nl;
        featT[((size_t)b * NN + ntl * 32 + nr) * CC + ct * 32 + cc] = tile[cc][nr];
    }
}

// ------ stage 1a: keypoint-clique edges [0, EKP).
//   48 distinct node rows staged ONCE in LDS; A from ds_read, W in LDS.
__global__ __launch_bounds__(512, 1) void k_edge_kp(
    const float* __restrict__ featT, const int* __restrict__ pairs,
    const uint4* __restrict__ wglob, const float* __restrict__ b1,
    float* __restrict__ hstore, float* __restrict__ Ssum,
    float* __restrict__ S2sum, int E, int EKP)
{
    __shared__ ushort Wsh[40960];       // 80 KB W hi||lo
    __shared__ float Rows[48 * ROWP];   // 62.2 KB kp rows (pad 4 -> 2-way banks)
    __shared__ int kpn[48];

    int t = threadIdx.x;
    int b  = blockIdx.x % BB;
    int e0 = (blockIdx.x / BB) * 128;

    {   // W staging: 5120 uint4, 10 per thread
        uint4* dst = (uint4*)Wsh;
        #pragma unroll
        for (int k = 0; k < 10; ++k)
            dst[t + k * 512] = wglob[t + k * 512];
    }
    if (t < 48) kpn[t] = pairs[((size_t)b * E + t * 47) * 2];
    __syncthreads();

    {   // row staging: 48 rows x 80 float4
        const float4* src = (const float4*)featT;
        #pragma unroll
        for (int k = 0; k < 8; ++k) {
            int idx = t + k * 512;
            if (idx < 48 * 80) {
                int slot = idx / 80, c4 = idx - slot * 80;
                float4 v = src[((size_t)b * NN + kpn[slot]) * 80 + c4];
                *(float4*)&Rows[slot * ROWP + c4 * 4] = v;
            }
        }
    }

    int wave = t >> 6, lane = t & 63;
    int q = lane >> 4, r = lane & 15;

    int eg = e0 + wave * 16 + r;
    int ec = eg < EKP ? eg : EKP - 1;
    int a = ec / 47, k = ec - a * 47;
    int y = k + (k >= a ? 1 : 0);
    const float* rI = &Rows[a * ROWP + q * 8];
    const float* rJ = &Rows[y * ROWP + q * 8];

    v4f acc[4];
    #pragma unroll
    for (int nt = 0; nt < 4; ++nt) acc[nt] = (v4f)0.f;

    __syncthreads();   // Rows + Wsh ready

    const bfrag* WH = (const bfrag*)Wsh;
    const bfrag* WL = (const bfrag*)(Wsh + 20480);

    #pragma unroll
    for (int ks = 0; ks < 10; ++ks) {
        float4 fi0 = *(const float4*)(rI + ks * 32);
        float4 fi1 = *(const float4*)(rI + ks * 32 + 4);
        float4 fj0 = *(const float4*)(rJ + ks * 32);
        float4 fj1 = *(const float4*)(rJ + ks * 32 + 4);
        float df[8];
        df[0] = fabsf(fi0.x - fj0.x); df[1] = fabsf(fi0.y - fj0.y);
        df[2] = fabsf(fi0.z - fj0.z); df[3] = fabsf(fi0.w - fj0.w);
        df[4] = fabsf(fi1.x - fj1.x); df[5] = fabsf(fi1.y - fj1.y);
        df[6] = fabsf(fi1.z - fj1.z); df[7] = fabsf(fi1.w - fj1.w);

        bfrag ah, al;
        #pragma unroll
        for (int kk = 0; kk < 8; ++kk) {
            __bf16 h = (__bf16)df[kk];
            ah[kk] = h;
            al[kk] = (__bf16)(df[kk] - (float)h);
        }
        #pragma unroll
        for (int nt = 0; nt < 4; ++nt) {
            bfrag bh = WH[((ks * 4 + nt) << 6) + lane];
            bfrag bl = WL[((ks * 4 + nt) << 6) + lane];
            acc[nt] = __builtin_amdgcn_mfma_f32_16x16x32_bf16(ah, bh, acc[nt], 0, 0, 0);
            acc[nt] = __builtin_amdgcn_mfma_f32_16x16x32_bf16(ah, bl, acc[nt], 0, 0, 0);
            acc[nt] = __builtin_amdgcn_mfma_f32_16x16x32_bf16(al, bh, acc[nt], 0, 0, 0);
        }
    }

    float b1v[4];
    #pragma unroll
    for (int nt = 0; nt < 4; ++nt) b1v[nt] = b1[nt * 16 + r];
    float ps[4], ps2[4];
    #pragma unroll
    for (int nt = 0; nt < 4; ++nt) { ps[nt] = 0.f; ps2[nt] = 0.f; }

    #pragma unroll
    for (int reg = 0; reg < 4; ++reg) {
        int e = e0 + wave * 16 + q * 4 + reg;
        if (e < EKP) {
            float* hp = hstore + ((size_t)b * E + e) * PH + r;
            #pragma unroll
            for (int nt = 0; nt < 4; ++nt) {
                float v = acc[nt][reg] + b1v[nt];
                hp[nt * 16] = v;
                ps[nt] += v;
                ps2[nt] = fmaf(v, v, ps2[nt]);
            }
        }
    }

    __syncthreads();
    float* sS  = Rows;
    float* sS2 = Rows + PH;
    if (t < PH) { sS[t] = 0.f; sS2[t] = 0.f; }
    __syncthreads();
    #pragma unroll
    for (int nt = 0; nt < 4; ++nt) {
        atomicAdd(&sS[nt * 16 + r],  ps[nt]);
        atomicAdd(&sS2[nt * 16 + r], ps2[nt]);
    }
    __syncthreads();
    if (t < PH) {
        atomicAdd(&Ssum[b * PH + t],  sS[t]);
        atomicAdd(&S2sum[b * PH + t], sS2[t]);
    }
}

// ------ stage 1b: 8-neigh edges. FULL upfront prefetch: all 40 A-loads
//   (160 f32 regs/lane) issued before one barrier drain -> latency paid
//   ONCE per block, K-loop is pure LDS+MFMA compute.
__global__ __launch_bounds__(256, 2) void k_edge_ng(
    const float* __restrict__ featT, const int* __restrict__ pairs,
    const uint4* __restrict__ wglob, const float* __restrict__ b1,
    float* __restrict__ hstore, float* __restrict__ Ssum,
    float* __restrict__ S2sum, int E, int EKP)
{
    __shared__ ushort Wsh[40960];       // 80 KB W hi||lo

    int t = threadIdx.x;
    {   // W staging: 5120 uint4, 20 per thread
        uint4* dst = (uint4*)Wsh;
        #pragma unroll
        for (int k = 0; k < 20; ++k)
            dst[t + k * 256] = wglob[t + k * 256];
    }

    int b  = blockIdx.x % BB;
    int e0 = EKP + (blockIdx.x / BB) * 64;
    int wave = t >> 6, lane = t & 63;
    int q = lane >> 4, r = lane & 15;

    int eg = e0 + wave * 16 + r;
    int ec = eg < E ? eg : E - 1;
    int ii = pairs[((size_t)b * E + ec) * 2 + 0];
    int jj = pairs[((size_t)b * E + ec) * 2 + 1];
    const float* pI = featT + ((size_t)b * NN + ii) * CC + q * 8;
    const float* pJ = featT + ((size_t)b * NN + jj) * CC + q * 8;

    // issue ALL A-loads now (40 dwordx4 in flight per lane-group)
    float fi[10][8], fj[10][8];
    #pragma unroll
    for (int ks = 0; ks < 10; ++ks) {
        const float4* a = (const float4*)(pI + ks * 32);
        const float4* c = (const float4*)(pJ + ks * 32);
        *(float4*)&fi[ks][0] = a[0];
        *(float4*)&fi[ks][4] = a[1];
        *(float4*)&fj[ks][0] = c[0];
        *(float4*)&fj[ks][4] = c[1];
    }

    v4f acc[4];
    #pragma unroll
    for (int nt = 0; nt < 4; ++nt) acc[nt] = (v4f)0.f;

    __syncthreads();   // single drain: Wsh + all prefetches resident

    const bfrag* WH = (const bfrag*)Wsh;
    const bfrag* WL = (const bfrag*)(Wsh + 20480);

    #pragma unroll
    for (int ks = 0; ks < 10; ++ks) {
        bfrag ah, al;
        #pragma unroll
        for (int kk = 0; kk < 8; ++kk) {
            float d = fabsf(fi[ks][kk] - fj[ks][kk]);
            __bf16 h = (__bf16)d;
            ah[kk] = h;
            al[kk] = (__bf16)(d - (float)h);
        }
        #pragma unroll
        for (int nt = 0; nt < 4; ++nt) {
            bfrag bh = WH[((ks * 4 + nt) << 6) + lane];
            bfrag bl = WL[((ks * 4 + nt) << 6) + lane];
            acc[nt] = __builtin_amdgcn_mfma_f32_16x16x32_bf16(ah, bh, acc[nt], 0, 0, 0);
            acc[nt] = __builtin_amdgcn_mfma_f32_16x16x32_bf16(ah, bl, acc[nt], 0, 0, 0);
            acc[nt] = __builtin_amdgcn_mfma_f32_16x16x32_bf16(al, bh, acc[nt], 0, 0, 0);
        }
    }

    float b1v[4];
    #pragma unroll
    for (int nt = 0; nt < 4; ++nt) b1v[nt] = b1[nt * 16 + r];
    float ps[4], ps2[4];
    #pragma unroll
    for (int nt = 0; nt < 4; ++nt) { ps[nt] = 0.f; ps2[nt] = 0.f; }

    #pragma unroll
    for (int reg = 0; reg < 4; ++reg) {
        int e = e0 + wave * 16 + q * 4 + reg;
        if (e < E) {
            float* hp = hstore + ((size_t)b * E + e) * PH + r;
            #pragma unroll
            for (int nt = 0; nt < 4; ++nt) {
                float v = acc[nt][reg] + b1v[nt];
                hp[nt * 16] = v;
                ps[nt] += v;
                ps2[nt] = fmaf(v, v, ps2[nt]);
            }
        }
    }

    __syncthreads();
    float* sS  = (float*)Wsh;
    float* sS2 = ((float*)Wsh) + PH;
    if (t < PH) { sS[t] = 0.f; sS2[t] = 0.f; }
    __syncthreads();
    #pragma unroll
    for (int nt = 0; nt < 4; ++nt) {
        atomicAdd(&sS[nt * 16 + r],  ps[nt]);
        atomicAdd(&sS2[nt * 16 + r], ps2[nt]);
    }
    __syncthreads();
    if (t < PH) {
        atomicAdd(&Ssum[b * PH + t],  sS[t]);
        atomicAdd(&S2sum[b * PH + t], sS2[t]);
    }
}

// -- stage 3: BN-final (in-block) + edge value + ELL scatter --------------
__global__ __launch_bounds__(256) void k_edge_val(
    const float* __restrict__ hstore, const float* __restrict__ Ssum,
    const float* __restrict__ S2sum, const float* __restrict__ gamma,
    const float* __restrict__ beta, const float* __restrict__ w2,
    const float* __restrict__ b2, const int* __restrict__ pairs,
    int* __restrict__ cnt, int* __restrict__ ecol, float* __restrict__ eval_,
    int E)
{
    __shared__ float ca[PH], cb[PH];
    int b = blockIdx.x % BB;
    int e = (blockIdx.x / BB) * 256 + threadIdx.x;
    if (threadIdx.x < PH) {
        int l = threadIdx.x;
        float mu = Ssum[b * PH + l] / E;
        float var = S2sum[b * PH + l] / E - mu * mu;
        float A = rsqrtf(var + 1e-5f) * gamma[l];
        ca[l] = A;
        cb[l] = beta[l] - mu * A;
    }
    __syncthreads();
    if (e >= E) return;
    const float4* hp = (const float4*)(hstore + ((size_t)b * E + e) * PH);
    float acc = 0.f;
    #pragma unroll
    for (int l4 = 0; l4 < 16; ++l4) {
        float4 v = hp[l4];
        float vv[4] = {v.x, v.y, v.z, v.w};
        #pragma unroll
        for (int c = 0; c < 4; ++c) {
            int l = l4 * 4 + c;
            float x = fmaf(vv[c], ca[l], cb[l]);
            x = x > 0.f ? x : 0.f;
            acc = fmaf(x, w2[l], acc);
        }
    }
    float edge = 1.f / (1.f + __expf(-(acc + b2[0])));
    const int* cp = pairs + ((size_t)b * E + e) * 2;
    int i = cp[0], j = cp[1];
    int row = b * NN + i;
    int slot = atomicAdd(&cnt[row], 1);
    if (slot < ELLW) {
        ecol[row * ELLW + slot]  = j;
        eval_[row * ELLW + slot] = edge;
    }
}

// ------ stage 4: g1 = featT @ gc1_w  (split-bf16 MFMA, upfront prefetch) -
__global__ __launch_bounds__(256, 2) void k_gc1(
    const float* __restrict__ featT, const __bf16* __restrict__ gwhi,
    const __bf16* __restrict__ gwlo, float* __restrict__ g1)
{
    __shared__ ushort WG[40960];   // 80 KB: hi-half, lo-half

    int t = threadIdx.x;
    int b = blockIdx.x % BB;
    int rem = blockIdx.x / BB;     // 0..31
    int half = rem & 1;
    int m0 = b * NN + (rem >> 1) * 64;

    {
        uint4* dst = (uint4*)WG;
        const uint4* sh = (const uint4*)gwhi;
        const uint4* sl = (const uint4*)gwlo;
        #pragma unroll
        for (int k = 0; k < 10; ++k) {
            int u = t + k * 256;
            int chunk = u >> 6, v = u & 63;
            int ks = chunk >> 2, ntp = chunk & 3;
            int src = (ks * 8 + half * 4 + ntp) * 64 + v;
            dst[u]        = sh[src];
            dst[2560 + u] = sl[src];
        }
    }

    int wave = t >> 6, lane = t & 63;
    int q = lane >> 4, r = lane & 15;
    const float* fp = featT + (size_t)(m0 + wave * 16 + r) * CC + q * 8;

    // upfront prefetch of all 10 K-steps (80 f32 regs)
    float fa[10][8];
    #pragma unroll
    for (int ks = 0; ks < 10; ++ks) {
        const float4* p = (const float4*)(fp + ks * 32);
        *(float4*)&fa[ks][0] = p[0];
        *(float4*)&fa[ks][4] = p[1];
    }

    v4f acc[4];
    #pragma unroll
    for (int nt = 0; nt < 4; ++nt) acc[nt] = (v4f)0.f;

    __syncthreads();   // WG + prefetches resident

    const bfrag* WGH = (const bfrag*)WG;
    const bfrag* WGL = (const bfrag*)(WG + 20480);

    #pragma unroll
    for (int ks = 0; ks < 10; ++ks) {
        bfrag ah, al;
        #pragma unroll
        for (int kk = 0; kk < 8; ++kk) {
            float d = fa[ks][kk];
            __bf16 h = (__bf16)d;
            ah[kk] = h;
            al[kk] = (__bf16)(d - (float)h);
        }
        #pragma unroll
        for (int nt = 0; nt < 4; ++nt) {
            bfrag bh = WGH[((ks * 4 + nt) << 6) + lane];
            bfrag bl = WGL[((ks * 4 + nt) << 6) + lane];
            acc[nt] = __builtin_amdgcn_mfma_f32_16x16x32_bf16(ah, bh, acc[nt], 0, 0, 0);
            acc[nt] = __builtin_amdgcn_mfma_f32_16x16x32_bf16(ah, bl, acc[nt], 0, 0, 0);
            acc[nt] = __builtin_amdgcn_mfma_f32_16x16x32_bf16(al, bh, acc[nt], 0, 0, 0);
        }
    }
    #pragma unroll
    for (int nt = 0; nt < 4; ++nt) {
        #pragma unroll
        for (int reg = 0; reg < 4; ++reg) {
            int m = m0 + wave * 16 + q * 4 + reg;
            g1[(size_t)m * GH + (half * 4 + nt) * 16 + r] = acc[nt][reg];
        }
    }
}

// ------- stage 5: h1 = leaky(adj @ g1); g2 = h1 @ gc2_w (1 node/block) ---
__global__ __launch_bounds__(128) void k_spmm1(
    const float* __restrict__ g1, const int* __restrict__ cnt,
    const int* __restrict__ ecol, const float* __restrict__ eval_,
    const float* __restrict__ w2g, float* __restrict__ g2)
{
    __shared__ float tmp[2];
    int tid = threadIdx.x;
    int b = blockIdx.x % BB;
    int node = b * NN + blockIdx.x / BB;
    float wv = w2g[tid];
    int c = cnt[node];
    const int* ec = ecol + (size_t)node * ELLW;
    const float* ev = eval_ + (size_t)node * ELLW;
    float acc = 0.f;
    int s = 0;
    for (; s + 4 <= c; s += 4) {
        int j0 = ec[s], j1 = ec[s + 1], j2 = ec[s + 2], j3 = ec[s + 3];
        float v0 = ev[s], v1 = ev[s + 1], v2 = ev[s + 2], v3 = ev[s + 3];
        float a0 = g1[((size_t)b * NN + j0) * GH + tid];
        float a1 = g1[((size_t)b * NN + j1) * GH + tid];
        float a2 = g1[((size_t)b * NN + j2) * GH + tid];
        float a3 = g1[((size_t)b * NN + j3) * GH + tid];
        acc = fmaf(v0, a0, acc); acc = fmaf(v1, a1, acc);
        acc = fmaf(v2, a2, acc); acc = fmaf(v3, a3, acc);
    }
    for (; s < c; ++s) {
        int j = ec[s];
        acc = fmaf(ev[s], g1[((size_t)b * NN + j) * GH + tid], acc);
    }
    float h1 = acc > 0.f ? acc : 0.2f * acc;
    float p = h1 * wv;
    #pragma unroll
    for (int off = 32; off >= 1; off >>= 1) p += __shfl_down(p, off, 64);
    if ((tid & 63) == 0) tmp[tid >> 6] = p;
    __syncthreads();
    if (tid == 0) g2[node] = tmp[0] + tmp[1];
}

// ------------- stage 6: out = sigmoid(adj @ g2) (1 wave/node, lane=slot) -
__global__ __launch_bounds__(64) void k_spmm2(
    const float* __restrict__ g2, const int* __restrict__ cnt,
    const int* __restrict__ ecol, const float* __restrict__ eval_,
    float* __restrict__ out)
{
    int b = blockIdx.x % BB;
    int node = b * NN + blockIdx.x / BB;
    int lane = threadIdx.x;
    int c = cnt[node];
    float p = 0.f;
    if (lane < c) {
        int j = ecol[(size_t)node * ELLW + lane];
        p = eval_[(size_t)node * ELLW + lane] * g2[b * NN + j];
    }
    #pragma unroll
    for (int off = 32; off >= 1; off >>= 1) p += __shfl_down(p, off, 64);
    if (lane == 0) out[node] = 1.f / (1.f + __expf(-p));
}

extern "C" void kernel_launch(void* const* d_in, const int* in_sizes, int n_in,
                              void* d_out, int out_size, void* d_ws, size_t ws_size,
                              hipStream_t stream)
{
    const float* search = (const float*)d_in[0];
    const float* xcorr  = (const float*)d_in[1];
    const int*   pairs  = (const int*)d_in[2];
    const float* w1     = (const float*)d_in[3];
    const float* b1     = (const float*)d_in[4];
    const float* gamma  = (const float*)d_in[5];
    const float* beta   = (const float*)d_in[6];
    const float* w2     = (const float*)d_in[7];
    const float* b2     = (const float*)d_in[8];
    const float* gc1w   = (const float*)d_in[9];
    const float* gc2w   = (const float*)d_in[10];
    float* out = (float*)d_out;

    int E   = in_sizes[2] / (BB * 2);    // 10068
    int EKP = E - NENG;                  // 2256 keypoint-clique edges
    int nb   = (E + 255) / 256;          // 40
    int nbKP = (EKP + 127) / 128;        // 18
    int nbNG = (NENG + 63) / 64;         // 123

    char* ws = (char*)d_ws;
    size_t off = 0;
    auto alloc = [&](size_t bytes) {
        size_t o = off;
        off += (bytes + 255) & ~(size_t)255;
        return o;
    };
    __bf16* whi   = (__bf16*)(ws + alloc(10 * 4 * 64 * 8 * 2));   // 40960 B
    __bf16* wlo   = (__bf16*)(ws + alloc(10 * 4 * 64 * 8 * 2));   // contiguous after whi
    __bf16* gwhi  = (__bf16*)(ws + alloc(10 * 8 * 64 * 8 * 2));
    __bf16* gwlo  = (__bf16*)(ws + alloc(10 * 8 * 64 * 8 * 2));
    float* featT  = (float*)(ws + alloc((size_t)BB * NN * CC * 4));
    float* hstore = (float*)(ws + alloc((size_t)BB * E * PH * 4));
    float* Ssum   = (float*)(ws + alloc(BB * PH * 4));
    float* S2sum  = (float*)(ws + alloc(BB * PH * 4));
    int*   cnt    = (int*)(ws + alloc(BB * NN * 4));
    int*   ecol   = (int*)(ws + alloc((size_t)BB * NN * ELLW * 4));
    float* eval_  = (float*)(ws + alloc((size_t)BB * NN * ELLW * 4));
    float* g1     = (float*)(ws + alloc((size_t)BB * NN * GH * 4));
    float* g2     = (float*)(ws + alloc(BB * NN * 4));
    (void)ws_size; (void)n_in; (void)out_size;

    k_prep<<<dim3(160), dim3(256), 0, stream>>>(w1, gc1w, whi, wlo, gwhi, gwlo,
                                                cnt, Ssum, S2sum);
    k_transpose<<<dim3(BB * 320), dim3(256), 0, stream>>>(search, xcorr, featT);
    k_edge_kp<<<dim3(BB * nbKP), dim3(512), 0, stream>>>(featT, pairs,
                                                         (const uint4*)whi, b1,
                                                         hstore, Ssum, S2sum, E, EKP);
    k_edge_ng<<<dim3(BB * nbNG), dim3(256), 0, stream>>>(featT, pairs,
                                                         (const uint4*)whi, b1,
                                                         hstore, Ssum, S2sum, E, EKP);
    k_edge_val<<<dim3(BB * nb), dim3(256), 0, stream>>>(hstore, Ssum, S2sum,
                                                        gamma, beta, w2, b2,
                                                        pairs, cnt, ecol, eval_, E);
    k_gc1<<<dim3(BB * 32), dim3(256), 0, stream>>>(featT, gwhi, gwlo, g1);
    k_spmm1<<<dim3(BB * NN), dim3(128), 0, stream>>>(g1, cnt, ecol, eval_, gc2w, g2);
    k_spmm2<<<dim3(BB * NN), dim3(64), 0, stream>>>(g2, cnt, ecol, eval_, out);
}

// Round 14
// 190.646 us; speedup vs baseline: 1.1982x; 1.1982x over previous
//
#include <hip/hip_runtime.h>
#include <hip/hip_bf16.h>

#define BB 16
#define NN 1024
#define CS 256
#define CX 64
#define CC 320
#define PH 64
#define GH 128
#define ELLW 64
#define NENG 7812    // 8-neigh edges per image (H=W=32)
#define ROWP 324     // padded kp row stride in floats (320 + 4)
#define RSTR 100     // ng LDS row stride in floats (96 + 4)

typedef __hip_bfloat16 bf16;
typedef __attribute__((ext_vector_type(8))) __bf16 bfrag;   // 8 bf16 = 4 VGPRs
typedef __attribute__((ext_vector_type(4))) float v4f;

// ---------------- prep: pack W1 + gc1_w (hi/lo split) into B-frag order --
__global__ __launch_bounds__(256) void k_prep(
    const float* __restrict__ w1, const float* __restrict__ gc1w,
    __bf16* __restrict__ whi, __bf16* __restrict__ wlo,
    __bf16* __restrict__ gwhi, __bf16* __restrict__ gwlo,
    int* __restrict__ cnt, float* __restrict__ Ssum, float* __restrict__ S2sum)
{
    int idx = blockIdx.x * 256 + threadIdx.x;
    if (idx < 10 * 4 * 64 * 8) {          // W1: PH=64 -> 4 ntiles
        int j    = idx & 7;
        int lane = (idx >> 3) & 63;
        int nt   = (idx >> 9) & 3;
        int ks   = idx >> 11;
        int k = ks * 32 + (lane >> 4) * 8 + j;
        int n = nt * 16 + (lane & 15);
        float w = w1[k * PH + n];
        __bf16 h = (__bf16)w;
        whi[idx] = h;
        wlo[idx] = (__bf16)(w - (float)h);
    }
    if (idx < 10 * 8 * 64 * 8) {          // gc1_w: GH=128 -> 8 ntiles
        int j    = idx & 7;
        int lane = (idx >> 3) & 63;
        int nt   = (idx >> 9) & 7;
        int ks   = idx >> 12;
        int k = ks * 32 + (lane >> 4) * 8 + j;
        int n = nt * 16 + (lane & 15);
        float w = gc1w[k * GH + n];
        __bf16 h = (__bf16)w;
        gwhi[idx] = h;
        gwlo[idx] = (__bf16)(w - (float)h);
    }
    if (idx < BB * NN) cnt[idx] = 0;
    if (idx < BB * PH) { Ssum[idx] = 0.f; S2sum[idx] = 0.f; }
}

// ---------------- transpose: [B,C,N] -> featT [B,N,C] f32 ----------------
__global__ __launch_bounds__(256) void k_transpose(
    const float* __restrict__ search, const float* __restrict__ xcorr,
    float* __restrict__ featT)
{
    __shared__ float tile[32][33];
    int blk = blockIdx.x;
    int b   = blk % BB;
    int rem = blk / BB;       // 0..319
    int ct  = rem >> 5;       // 10 channel tiles
    int ntl = rem & 31;       // 32 node tiles
    int tid = threadIdx.x;
    int cl = tid >> 5, nl = tid & 31;
    const float* sb = search + (size_t)b * CS * NN;
    const float* xb = xcorr + (size_t)b * CX * NN;
    #pragma unroll
    for (int f = 0; f < 4; ++f) {
        int c = ct * 32 + cl + f * 8;
        int n = ntl * 32 + nl;
        float v = (c < CS) ? sb[(size_t)c * NN + n] : xb[(size_t)(c - CS) * NN + n];
        tile[cl + f * 8][nl] = v;
    }
    __syncthreads();
    #pragma unroll
    for (int f = 0; f < 4; ++f) {
        int nr = cl + f * 8;
        int cc = nl;
        featT[((size_t)b * NN + ntl * 32 + nr) * CC + ct * 32 + cc] = tile[cc][nr];
    }
}

// ------ stage 1a: keypoint-clique edges [0, EKP).
//   48 distinct node rows staged ONCE in LDS; A from ds_read, W in LDS.
__global__ __launch_bounds__(512, 1) void k_edge_kp(
    const float* __restrict__ featT, const int* __restrict__ pairs,
    const uint4* __restrict__ wglob, const float* __restrict__ b1,
    float* __restrict__ hstore, float* __restrict__ Ssum,
    float* __restrict__ S2sum, int E, int EKP)
{
    __shared__ ushort Wsh[40960];       // 80 KB W hi||lo
    __shared__ float Rows[48 * ROWP];   // 62.2 KB kp rows (pad 4 -> 2-way banks)
    __shared__ int kpn[48];

    int t = threadIdx.x;
    int b  = blockIdx.x % BB;
    int e0 = (blockIdx.x / BB) * 128;

    {   // W staging: 5120 uint4, 10 per thread
        uint4* dst = (uint4*)Wsh;
        #pragma unroll
        for (int k = 0; k < 10; ++k)
            dst[t + k * 512] = wglob[t + k * 512];
    }
    if (t < 48) kpn[t] = pairs[((size_t)b * E + t * 47) * 2];
    __syncthreads();

    {   // row staging: 48 rows x 80 float4
        const float4* src = (const float4*)featT;
        #pragma unroll
        for (int k = 0; k < 8; ++k) {
            int idx = t + k * 512;
            if (idx < 48 * 80) {
                int slot = idx / 80, c4 = idx - slot * 80;
                float4 v = src[((size_t)b * NN + kpn[slot]) * 80 + c4];
                *(float4*)&Rows[slot * ROWP + c4 * 4] = v;
            }
        }
    }

    int wave = t >> 6, lane = t & 63;
    int q = lane >> 4, r = lane & 15;

    int eg = e0 + wave * 16 + r;
    int ec = eg < EKP ? eg : EKP - 1;
    int a = ec / 47, k = ec - a * 47;
    int y = k + (k >= a ? 1 : 0);
    const float* rI = &Rows[a * ROWP + q * 8];
    const float* rJ = &Rows[y * ROWP + q * 8];

    v4f acc[4];
    #pragma unroll
    for (int nt = 0; nt < 4; ++nt) acc[nt] = (v4f)0.f;

    __syncthreads();   // Rows + Wsh ready

    const bfrag* WH = (const bfrag*)Wsh;
    const bfrag* WL = (const bfrag*)(Wsh + 20480);

    #pragma unroll
    for (int ks = 0; ks < 10; ++ks) {
        float4 fi0 = *(const float4*)(rI + ks * 32);
        float4 fi1 = *(const float4*)(rI + ks * 32 + 4);
        float4 fj0 = *(const float4*)(rJ + ks * 32);
        float4 fj1 = *(const float4*)(rJ + ks * 32 + 4);
        float df[8];
        df[0] = fabsf(fi0.x - fj0.x); df[1] = fabsf(fi0.y - fj0.y);
        df[2] = fabsf(fi0.z - fj0.z); df[3] = fabsf(fi0.w - fj0.w);
        df[4] = fabsf(fi1.x - fj1.x); df[5] = fabsf(fi1.y - fj1.y);
        df[6] = fabsf(fi1.z - fj1.z); df[7] = fabsf(fi1.w - fj1.w);

        bfrag ah, al;
        #pragma unroll
        for (int kk = 0; kk < 8; ++kk) {
            __bf16 h = (__bf16)df[kk];
            ah[kk] = h;
            al[kk] = (__bf16)(df[kk] - (float)h);
        }
        #pragma unroll
        for (int nt = 0; nt < 4; ++nt) {
            bfrag bh = WH[((ks * 4 + nt) << 6) + lane];
            bfrag bl = WL[((ks * 4 + nt) << 6) + lane];
            acc[nt] = __builtin_amdgcn_mfma_f32_16x16x32_bf16(ah, bh, acc[nt], 0, 0, 0);
            acc[nt] = __builtin_amdgcn_mfma_f32_16x16x32_bf16(ah, bl, acc[nt], 0, 0, 0);
            acc[nt] = __builtin_amdgcn_mfma_f32_16x16x32_bf16(al, bh, acc[nt], 0, 0, 0);
        }
    }

    float b1v[4];
    #pragma unroll
    for (int nt = 0; nt < 4; ++nt) b1v[nt] = b1[nt * 16 + r];
    float ps[4], ps2[4];
    #pragma unroll
    for (int nt = 0; nt < 4; ++nt) { ps[nt] = 0.f; ps2[nt] = 0.f; }

    #pragma unroll
    for (int reg = 0; reg < 4; ++reg) {
        int e = e0 + wave * 16 + q * 4 + reg;
        if (e < EKP) {
            float* hp = hstore + ((size_t)b * E + e) * PH + r;
            #pragma unroll
            for (int nt = 0; nt < 4; ++nt) {
                float v = acc[nt][reg] + b1v[nt];
                hp[nt * 16] = v;
                ps[nt] += v;
                ps2[nt] = fmaf(v, v, ps2[nt]);
            }
        }
    }

    __syncthreads();
    float* sS  = Rows;
    float* sS2 = Rows + PH;
    if (t < PH) { sS[t] = 0.f; sS2[t] = 0.f; }
    __syncthreads();
    #pragma unroll
    for (int nt = 0; nt < 4; ++nt) {
        atomicAdd(&sS[nt * 16 + r],  ps[nt]);
        atomicAdd(&sS2[nt * 16 + r], ps2[nt]);
    }
    __syncthreads();
    if (t < PH) {
        atomicAdd(&Ssum[b * PH + t],  sS[t]);
        atomicAdd(&S2sum[b * PH + t], sS2[t]);
    }
}

// ------ stage 1b: 8-neigh edges as a STENCIL. Block = (image, 2-row strip).
//   Rows [2s-1, 2s+2] (128 nodes) staged cooperatively in LDS in 4 channel
//   phases; wave = direction; K-loop = ds_read + MFMA ONLY (zero global).
__global__ __launch_bounds__(512, 1) void k_edge_ng(
    const float* __restrict__ featT, const uint4* __restrict__ wglob,
    const float* __restrict__ b1, float* __restrict__ hstore,
    float* __restrict__ Ssum, float* __restrict__ S2sum, int E, int EKP)
{
    __shared__ ushort Wsh[40960];        // 80 KB W hi||lo
    __shared__ float Rows[128 * RSTR];   // 51.2 KB: 128 nodes x 96ch phase

    int t = threadIdx.x;
    int b = blockIdx.x % BB;
    int s = blockIdx.x / BB;             // strip 0..15, image rows 2s,2s+1

    {   // W staging: 5120 uint4, 10 per thread
        uint4* dst = (uint4*)Wsh;
        #pragma unroll
        for (int k = 0; k < 10; ++k)
            dst[t + k * 512] = wglob[t + k * 512];
    }

    // direction tables: order (-1,-1)(-1,0)(-1,1)(0,-1)(0,1)(1,-1)(1,0)(1,1)
    const int dyT[8] = {-1,-1,-1, 0, 0, 1, 1, 1};
    const int dxT[8] = {-1, 0, 1,-1, 1,-1, 0, 1};
    const int pfT[8] = {0, 961, 1953, 2914, 3906, 4898, 5859, 6851};

    int wave = t >> 6, lane = t & 63;
    int q = lane >> 4, r = lane & 15;
    int dy = dyT[wave], dx = dxT[wave];
    int y0 = dy < 0 ? 1 : 0;
    int x0 = dx < 0 ? 1 : 0;
    int ww = (dx == 0) ? 32 : 31;
    int pf = pfT[wave];
    int yA = 2 * s;

    // per-lane LDS row pointers for the 4 mtiles
    const float* rowI[4];
    const float* rowJ[4];
    #pragma unroll
    for (int mt = 0; mt < 4; ++mt) {
        int x  = ((mt & 1) << 4) + r;
        int ni = (1 + (mt >> 1)) * 32 + x;
        int xj = x + dx; xj = xj < 0 ? 0 : (xj > 31 ? 31 : xj);
        int nj = (1 + (mt >> 1) + dy) * 32 + xj;
        rowI[mt] = &Rows[ni * RSTR + q * 8];
        rowJ[mt] = &Rows[nj * RSTR + q * 8];
    }

    v4f acc[4][4];
    #pragma unroll
    for (int mt = 0; mt < 4; ++mt)
        #pragma unroll
        for (int nt = 0; nt < 4; ++nt) acc[mt][nt] = (v4f)0.f;

    const bfrag* WH = (const bfrag*)Wsh;
    const bfrag* WL = (const bfrag*)(Wsh + 20480);

    #pragma unroll
    for (int p = 0; p < 4; ++p) {
        __syncthreads();                 // prev phase reads done (also W ready)
        const int ch0 = p * 96;
        const int nf4 = (p < 3) ? 24 : 8;
        for (int u = t; u < 128 * nf4; u += 512) {
            int node = u / nf4, c4 = u - node * nf4;
            int gy = yA - 1 + (node >> 5);
            if (gy >= 0 && gy < 32) {
                int gn = gy * 32 + (node & 31);
                float4 v = *(const float4*)&featT[((size_t)b * NN + gn) * CC
                                                  + ch0 + c4 * 4];
                *(float4*)&Rows[node * RSTR + c4 * 4] = v;
            }
        }
        __syncthreads();                 // staging visible

        const int ksBeg = p * 3;
        const int ksEnd = (p < 3) ? ksBeg + 3 : 10;
        #pragma unroll
        for (int ks = ksBeg; ks < ksEnd; ++ks) {
            int lc = ks * 32 - ch0;
            #pragma unroll
            for (int mt = 0; mt < 4; ++mt) {
                float4 fi0 = *(const float4*)(rowI[mt] + lc);
                float4 fi1 = *(const float4*)(rowI[mt] + lc + 4);
                float4 fj0 = *(const float4*)(rowJ[mt] + lc);
                float4 fj1 = *(const float4*)(rowJ[mt] + lc + 4);
                float df[8];
                df[0] = fabsf(fi0.x - fj0.x); df[1] = fabsf(fi0.y - fj0.y);
                df[2] = fabsf(fi0.z - fj0.z); df[3] = fabsf(fi0.w - fj0.w);
                df[4] = fabsf(fi1.x - fj1.x); df[5] = fabsf(fi1.y - fj1.y);
                df[6] = fabsf(fi1.z - fj1.z); df[7] = fabsf(fi1.w - fj1.w);

                bfrag ah, al;
                #pragma unroll
                for (int kk = 0; kk < 8; ++kk) {
                    __bf16 h = (__bf16)df[kk];
                    ah[kk] = h;
                    al[kk] = (__bf16)(df[kk] - (float)h);
                }
                #pragma unroll
                for (int nt = 0; nt < 4; ++nt) {
                    bfrag bh = WH[((ks * 4 + nt) << 6) + lane];
                    bfrag bl = WL[((ks * 4 + nt) << 6) + lane];
                    acc[mt][nt] = __builtin_amdgcn_mfma_f32_16x16x32_bf16(
                        ah, bh, acc[mt][nt], 0, 0, 0);
                    acc[mt][nt] = __builtin_amdgcn_mfma_f32_16x16x32_bf16(
                        ah, bl, acc[mt][nt], 0, 0, 0);
                    acc[mt][nt] = __builtin_amdgcn_mfma_f32_16x16x32_bf16(
                        al, bh, acc[mt][nt], 0, 0, 0);
                }
            }
        }
    }

    // epilogue: bias + masked store + BN partials
    float b1v[4];
    #pragma unroll
    for (int nt = 0; nt < 4; ++nt) b1v[nt] = b1[nt * 16 + r];
    float ps[4], ps2[4];
    #pragma unroll
    for (int nt = 0; nt < 4; ++nt) { ps[nt] = 0.f; ps2[nt] = 0.f; }

    #pragma unroll
    for (int mt = 0; mt < 4; ++mt) {
        int y = yA + (mt >> 1);
        #pragma unroll
        for (int reg = 0; reg < 4; ++reg) {
            int xi = ((mt & 1) << 4) + q * 4 + reg;
            bool valid = ((unsigned)(y + dy) < 32u) && ((unsigned)(xi + dx) < 32u);
            if (valid) {
                int e = EKP + pf + (y - y0) * ww + (xi - x0);
                float* hp = hstore + ((size_t)b * E + e) * PH + r;
                #pragma unroll
                for (int nt = 0; nt < 4; ++nt) {
                    float v = acc[mt][nt][reg] + b1v[nt];
                    hp[nt * 16] = v;
                    ps[nt] += v;
                    ps2[nt] = fmaf(v, v, ps2[nt]);
                }
            }
        }
    }

    __syncthreads();
    float* sS  = Rows;
    float* sS2 = Rows + PH;
    if (t < PH) { sS[t] = 0.f; sS2[t] = 0.f; }
    __syncthreads();
    #pragma unroll
    for (int nt = 0; nt < 4; ++nt) {
        atomicAdd(&sS[nt * 16 + r],  ps[nt]);
        atomicAdd(&sS2[nt * 16 + r], ps2[nt]);
    }
    __syncthreads();
    if (t < PH) {
        atomicAdd(&Ssum[b * PH + t],  sS[t]);
        atomicAdd(&S2sum[b * PH + t], sS2[t]);
    }
}

// -- stage 3: BN-final (in-block) + edge value + ELL scatter --------------
__global__ __launch_bounds__(256) void k_edge_val(
    const float* __restrict__ hstore, const float* __restrict__ Ssum,
    const float* __restrict__ S2sum, const float* __restrict__ gamma,
    const float* __restrict__ beta, const float* __restrict__ w2,
    const float* __restrict__ b2, const int* __restrict__ pairs,
    int* __restrict__ cnt, int* __restrict__ ecol, float* __restrict__ eval_,
    int E)
{
    __shared__ float ca[PH], cb[PH];
    int b = blockIdx.x % BB;
    int e = (blockIdx.x / BB) * 256 + threadIdx.x;
    if (threadIdx.x < PH) {
        int l = threadIdx.x;
        float mu = Ssum[b * PH + l] / E;
        float var = S2sum[b * PH + l] / E - mu * mu;
        float A = rsqrtf(var + 1e-5f) * gamma[l];
        ca[l] = A;
        cb[l] = beta[l] - mu * A;
    }
    __syncthreads();
    if (e >= E) return;
    const float4* hp = (const float4*)(hstore + ((size_t)b * E + e) * PH);
    float acc = 0.f;
    #pragma unroll
    for (int l4 = 0; l4 < 16; ++l4) {
        float4 v = hp[l4];
        float vv[4] = {v.x, v.y, v.z, v.w};
        #pragma unroll
        for (int c = 0; c < 4; ++c) {
            int l = l4 * 4 + c;
            float x = fmaf(vv[c], ca[l], cb[l]);
            x = x > 0.f ? x : 0.f;
            acc = fmaf(x, w2[l], acc);
        }
    }
    float edge = 1.f / (1.f + __expf(-(acc + b2[0])));
    const int* cp = pairs + ((size_t)b * E + e) * 2;
    int i = cp[0], j = cp[1];
    int row = b * NN + i;
    int slot = atomicAdd(&cnt[row], 1);
    if (slot < ELLW) {
        ecol[row * ELLW + slot]  = j;
        eval_[row * ELLW + slot] = edge;
    }
}

// ------ stage 4: g1 = featT @ gc1_w  (split-bf16 MFMA) -------------------
__global__ __launch_bounds__(256, 2) void k_gc1(
    const float* __restrict__ featT, const __bf16* __restrict__ gwhi,
    const __bf16* __restrict__ gwlo, float* __restrict__ g1)
{
    __shared__ ushort WG[40960];   // 80 KB: hi-half, lo-half

    int t = threadIdx.x;
    int b = blockIdx.x % BB;
    int rem = blockIdx.x / BB;     // 0..31
    int half = rem & 1;
    int m0 = b * NN + (rem >> 1) * 64;

    {
        uint4* dst = (uint4*)WG;
        const uint4* sh = (const uint4*)gwhi;
        const uint4* sl = (const uint4*)gwlo;
        #pragma unroll
        for (int k = 0; k < 10; ++k) {
            int u = t + k * 256;
            int chunk = u >> 6, v = u & 63;
            int ks = chunk >> 2, ntp = chunk & 3;
            int src = (ks * 8 + half * 4 + ntp) * 64 + v;
            dst[u]        = sh[src];
            dst[2560 + u] = sl[src];
        }
    }

    int wave = t >> 6, lane = t & 63;
    int q = lane >> 4, r = lane & 15;
    const float* fp = featT + (size_t)(m0 + wave * 16 + r) * CC + q * 8;

    float fa[2][8];
    auto LOADA = [&](int ks, int buf) {
        const float4* p = (const float4*)(fp + ks * 32);
        *(float4*)&fa[buf][0] = p[0];
        *(float4*)&fa[buf][4] = p[1];
    };

    v4f acc[4];
    #pragma unroll
    for (int nt = 0; nt < 4; ++nt) acc[nt] = (v4f)0.f;

    LOADA(0, 0);
    __syncthreads();

    const bfrag* WGH = (const bfrag*)WG;
    const bfrag* WGL = (const bfrag*)(WG + 20480);

    #pragma unroll
    for (int ks = 0; ks < 10; ++ks) {
        int cur = ks & 1;
        if (ks < 9) LOADA(ks + 1, cur ^ 1);
        bfrag ah, al;
        #pragma unroll
        for (int kk = 0; kk < 8; ++kk) {
            float d = fa[cur][kk];
            __bf16 h = (__bf16)d;
            ah[kk] = h;
            al[kk] = (__bf16)(d - (float)h);
        }
        #pragma unroll
        for (int nt = 0; nt < 4; ++nt) {
            bfrag bh = WGH[((ks * 4 + nt) << 6) + lane];
            bfrag bl = WGL[((ks * 4 + nt) << 6) + lane];
            acc[nt] = __builtin_amdgcn_mfma_f32_16x16x32_bf16(ah, bh, acc[nt], 0, 0, 0);
            acc[nt] = __builtin_amdgcn_mfma_f32_16x16x32_bf16(ah, bl, acc[nt], 0, 0, 0);
            acc[nt] = __builtin_amdgcn_mfma_f32_16x16x32_bf16(al, bh, acc[nt], 0, 0, 0);
        }
    }
    #pragma unroll
    for (int nt = 0; nt < 4; ++nt) {
        #pragma unroll
        for (int reg = 0; reg < 4; ++reg) {
            int m = m0 + wave * 16 + q * 4 + reg;
            g1[(size_t)m * GH + (half * 4 + nt) * 16 + r] = acc[nt][reg];
        }
    }
}

// ------- stage 5: h1 = leaky(adj @ g1); g2 = h1 @ gc2_w (1 node/block) ---
__global__ __launch_bounds__(128) void k_spmm1(
    const float* __restrict__ g1, const int* __restrict__ cnt,
    const int* __restrict__ ecol, const float* __restrict__ eval_,
    const float* __restrict__ w2g, float* __restrict__ g2)
{
    __shared__ float tmp[2];
    int tid = threadIdx.x;
    int b = blockIdx.x % BB;
    int node = b * NN + blockIdx.x / BB;
    float wv = w2g[tid];
    int c = cnt[node];
    const int* ec = ecol + (size_t)node * ELLW;
    const float* ev = eval_ + (size_t)node * ELLW;
    float acc = 0.f;
    int s = 0;
    for (; s + 4 <= c; s += 4) {
        int j0 = ec[s], j1 = ec[s + 1], j2 = ec[s + 2], j3 = ec[s + 3];
        float v0 = ev[s], v1 = ev[s + 1], v2 = ev[s + 2], v3 = ev[s + 3];
        float a0 = g1[((size_t)b * NN + j0) * GH + tid];
        float a1 = g1[((size_t)b * NN + j1) * GH + tid];
        float a2 = g1[((size_t)b * NN + j2) * GH + tid];
        float a3 = g1[((size_t)b * NN + j3) * GH + tid];
        acc = fmaf(v0, a0, acc); acc = fmaf(v1, a1, acc);
        acc = fmaf(v2, a2, acc); acc = fmaf(v3, a3, acc);
    }
    for (; s < c; ++s) {
        int j = ec[s];
        acc = fmaf(ev[s], g1[((size_t)b * NN + j) * GH + tid], acc);
    }
    float h1 = acc > 0.f ? acc : 0.2f * acc;
    float p = h1 * wv;
    #pragma unroll
    for (int off = 32; off >= 1; off >>= 1) p += __shfl_down(p, off, 64);
    if ((tid & 63) == 0) tmp[tid >> 6] = p;
    __syncthreads();
    if (tid == 0) g2[node] = tmp[0] + tmp[1];
}

// ------------- stage 6: out = sigmoid(adj @ g2) (1 wave/node, lane=slot) -
__global__ __launch_bounds__(64) void k_spmm2(
    const float* __restrict__ g2, const int* __restrict__ cnt,
    const int* __restrict__ ecol, const float* __restrict__ eval_,
    float* __restrict__ out)
{
    int b = blockIdx.x % BB;
    int node = b * NN + blockIdx.x / BB;
    int lane = threadIdx.x;
    int c = cnt[node];
    float p = 0.f;
    if (lane < c) {
        int j = ecol[(size_t)node * ELLW + lane];
        p = eval_[(size_t)node * ELLW + lane] * g2[b * NN + j];
    }
    #pragma unroll
    for (int off = 32; off >= 1; off >>= 1) p += __shfl_down(p, off, 64);
    if (lane == 0) out[node] = 1.f / (1.f + __expf(-p));
}

extern "C" void kernel_launch(void* const* d_in, const int* in_sizes, int n_in,
                              void* d_out, int out_size, void* d_ws, size_t ws_size,
                              hipStream_t stream)
{
    const float* search = (const float*)d_in[0];
    const float* xcorr  = (const float*)d_in[1];
    const int*   pairs  = (const int*)d_in[2];
    const float* w1     = (const float*)d_in[3];
    const float* b1     = (const float*)d_in[4];
    const float* gamma  = (const float*)d_in[5];
    const float* beta   = (const float*)d_in[6];
    const float* w2     = (const float*)d_in[7];
    const float* b2     = (const float*)d_in[8];
    const float* gc1w   = (const float*)d_in[9];
    const float* gc2w   = (const float*)d_in[10];
    float* out = (float*)d_out;

    int E   = in_sizes[2] / (BB * 2);    // 10068
    int EKP = E - NENG;                  // 2256 keypoint-clique edges
    int nb   = (E + 255) / 256;          // 40
    int nbKP = (EKP + 127) / 128;        // 18

    char* ws = (char*)d_ws;
    size_t off = 0;
    auto alloc = [&](size_t bytes) {
        size_t o = off;
        off += (bytes + 255) & ~(size_t)255;
        return o;
    };
    __bf16* whi   = (__bf16*)(ws + alloc(10 * 4 * 64 * 8 * 2));   // 40960 B
    __bf16* wlo   = (__bf16*)(ws + alloc(10 * 4 * 64 * 8 * 2));   // contiguous after whi
    __bf16* gwhi  = (__bf16*)(ws + alloc(10 * 8 * 64 * 8 * 2));
    __bf16* gwlo  = (__bf16*)(ws + alloc(10 * 8 * 64 * 8 * 2));
    float* featT  = (float*)(ws + alloc((size_t)BB * NN * CC * 4));
    float* hstore = (float*)(ws + alloc((size_t)BB * E * PH * 4));
    float* Ssum   = (float*)(ws + alloc(BB * PH * 4));
    float* S2sum  = (float*)(ws + alloc(BB * PH * 4));
    int*   cnt    = (int*)(ws + alloc(BB * NN * 4));
    int*   ecol   = (int*)(ws + alloc((size_t)BB * NN * ELLW * 4));
    float* eval_  = (float*)(ws + alloc((size_t)BB * NN * ELLW * 4));
    float* g1     = (float*)(ws + alloc((size_t)BB * NN * GH * 4));
    float* g2     = (float*)(ws + alloc(BB * NN * 4));
    (void)ws_size; (void)n_in; (void)out_size;

    k_prep<<<dim3(160), dim3(256), 0, stream>>>(w1, gc1w, whi, wlo, gwhi, gwlo,
                                                cnt, Ssum, S2sum);
    k_transpose<<<dim3(BB * 320), dim3(256), 0, stream>>>(search, xcorr, featT);
    k_edge_kp<<<dim3(BB * nbKP), dim3(512), 0, stream>>>(featT, pairs,
                                                         (const uint4*)whi, b1,
                                                         hstore, Ssum, S2sum, E, EKP);
    k_edge_ng<<<dim3(BB * 16), dim3(512), 0, stream>>>(featT, (const uint4*)whi,
                                                       b1, hstore, Ssum, S2sum,
                                                       E, EKP);
    k_edge_val<<<dim3(BB * nb), dim3(256), 0, stream>>>(hstore, Ssum, S2sum,
                                                        gamma, beta, w2, b2,
                                                        pairs, cnt, ecol, eval_, E);
    k_gc1<<<dim3(BB * 32), dim3(256), 0, stream>>>(featT, gwhi, gwlo, g1);
    k_spmm1<<<dim3(BB * NN), dim3(128), 0, stream>>>(g1, cnt, ecol, eval_, gc2w, g2);
    k_spmm2<<<dim3(BB * NN), dim3(64), 0, stream>>>(g2, cnt, ecol, eval_, out);
}

// Round 16
// 183.282 us; speedup vs baseline: 1.2464x; 1.0402x over previous
//
#include <hip/hip_runtime.h>
#include <hip/hip_bf16.h>

#define BB 16
#define NN 1024
#define CS 256
#define CX 64
#define CC 320
#define PH 64
#define GH 128
#define ELLW 64
#define NENG 7812    // 8-neigh edges per image (H=W=32)
#define ROWP 324     // padded kp row stride in floats (320 + 4)
#define RSTR 100     // ng LDS row stride in floats (96 + 4)

typedef __hip_bfloat16 bf16;
typedef __attribute__((ext_vector_type(8))) __bf16 bfrag;   // 8 bf16 = 4 VGPRs
typedef __attribute__((ext_vector_type(4))) float v4f;

// ---------------- prep: pack W1 + gc1_w (hi/lo split) into B-frag order --
__global__ __launch_bounds__(256) void k_prep(
    const float* __restrict__ w1, const float* __restrict__ gc1w,
    __bf16* __restrict__ whi, __bf16* __restrict__ wlo,
    __bf16* __restrict__ gwhi, __bf16* __restrict__ gwlo,
    int* __restrict__ cnt, float* __restrict__ Ssum, float* __restrict__ S2sum)
{
    int idx = blockIdx.x * 256 + threadIdx.x;
    if (idx < 10 * 4 * 64 * 8) {          // W1: PH=64 -> 4 ntiles
        int j    = idx & 7;
        int lane = (idx >> 3) & 63;
        int nt   = (idx >> 9) & 3;
        int ks   = idx >> 11;
        int k = ks * 32 + (lane >> 4) * 8 + j;
        int n = nt * 16 + (lane & 15);
        float w = w1[k * PH + n];
        __bf16 h = (__bf16)w;
        whi[idx] = h;
        wlo[idx] = (__bf16)(w - (float)h);
    }
    if (idx < 10 * 8 * 64 * 8) {          // gc1_w: GH=128 -> 8 ntiles
        int j    = idx & 7;
        int lane = (idx >> 3) & 63;
        int nt   = (idx >> 9) & 7;
        int ks   = idx >> 12;
        int k = ks * 32 + (lane >> 4) * 8 + j;
        int n = nt * 16 + (lane & 15);
        float w = gc1w[k * GH + n];
        __bf16 h = (__bf16)w;
        gwhi[idx] = h;
        gwlo[idx] = (__bf16)(w - (float)h);
    }
    if (idx < BB * NN) cnt[idx] = 0;
    if (idx < BB * PH) { Ssum[idx] = 0.f; S2sum[idx] = 0.f; }
}

// ---------------- transpose: [B,C,N] -> featT [B,N,C] f32 ----------------
__global__ __launch_bounds__(256) void k_transpose(
    const float* __restrict__ search, const float* __restrict__ xcorr,
    float* __restrict__ featT)
{
    __shared__ float tile[32][33];
    int blk = blockIdx.x;
    int b   = blk % BB;
    int rem = blk / BB;       // 0..319
    int ct  = rem >> 5;       // 10 channel tiles
    int ntl = rem & 31;       // 32 node tiles
    int tid = threadIdx.x;
    int cl = tid >> 5, nl = tid & 31;
    const float* sb = search + (size_t)b * CS * NN;
    const float* xb = xcorr + (size_t)b * CX * NN;
    #pragma unroll
    for (int f = 0; f < 4; ++f) {
        int c = ct * 32 + cl + f * 8;
        int n = ntl * 32 + nl;
        float v = (c < CS) ? sb[(size_t)c * NN + n] : xb[(size_t)(c - CS) * NN + n];
        tile[cl + f * 8][nl] = v;
    }
    __syncthreads();
    #pragma unroll
    for (int f = 0; f < 4; ++f) {
        int nr = cl + f * 8;
        int cc = nl;
        featT[((size_t)b * NN + ntl * 32 + nr) * CC + ct * 32 + cc] = tile[cc][nr];
    }
}

// ------ stage 1 (merged): kp-clique blocks [0, nKP) + ng-stencil blocks.
//   All A-operands via LDS (zero global gathers in K-loops); W in LDS;
//   bf16 hstore; fused BN partial sums (f32).
__global__ __launch_bounds__(512, 1) void k_edge(
    const float* __restrict__ featT, const int* __restrict__ pairs,
    const uint4* __restrict__ wglob, const float* __restrict__ b1,
    bf16* __restrict__ hstore, float* __restrict__ Ssum,
    float* __restrict__ S2sum, int E, int EKP, int nKP)
{
    __shared__ ushort Wsh[40960];        // 80 KB W hi||lo
    __shared__ float RowsBuf[48 * ROWP]; // 62.2 KB (ng uses first 51.2 KB)
    __shared__ int kpn[48];

    int t = threadIdx.x;
    int wave = t >> 6, lane = t & 63;
    int q = lane >> 4, r = lane & 15;

    {   // W staging: 5120 uint4, 10 per thread
        uint4* dst = (uint4*)Wsh;
        #pragma unroll
        for (int k = 0; k < 10; ++k)
            dst[t + k * 512] = wglob[t + k * 512];
    }
    const bfrag* WH = (const bfrag*)Wsh;
    const bfrag* WL = (const bfrag*)(Wsh + 20480);

    float b1v[4];
    #pragma unroll
    for (int nt = 0; nt < 4; ++nt) b1v[nt] = b1[nt * 16 + r];
    float ps[4], ps2[4];
    #pragma unroll
    for (int nt = 0; nt < 4; ++nt) { ps[nt] = 0.f; ps2[nt] = 0.f; }
    int b;

    if (blockIdx.x < nKP) {
        // ---------------- keypoint-clique branch ----------------
        b = blockIdx.x % BB;
        int e0 = (blockIdx.x / BB) * 128;
        if (t < 48) kpn[t] = pairs[((size_t)b * E + t * 47) * 2];
        __syncthreads();   // kpn + W ready

        {   // row staging: 48 rows x 80 float4
            const float4* src = (const float4*)featT;
            #pragma unroll
            for (int k = 0; k < 8; ++k) {
                int idx = t + k * 512;
                if (idx < 48 * 80) {
                    int slot = idx / 80, c4 = idx - slot * 80;
                    float4 v = src[((size_t)b * NN + kpn[slot]) * 80 + c4];
                    *(float4*)&RowsBuf[slot * ROWP + c4 * 4] = v;
                }
            }
        }

        int eg = e0 + wave * 16 + r;
        int ec = eg < EKP ? eg : EKP - 1;
        int a = ec / 47, k = ec - a * 47;
        int y = k + (k >= a ? 1 : 0);
        const float* rI = &RowsBuf[a * ROWP + q * 8];
        const float* rJ = &RowsBuf[y * ROWP + q * 8];

        v4f acc[4];
        #pragma unroll
        for (int nt = 0; nt < 4; ++nt) acc[nt] = (v4f)0.f;

        __syncthreads();   // rows ready

        #pragma unroll
        for (int ks = 0; ks < 10; ++ks) {
            float4 fi0 = *(const float4*)(rI + ks * 32);
            float4 fi1 = *(const float4*)(rI + ks * 32 + 4);
            float4 fj0 = *(const float4*)(rJ + ks * 32);
            float4 fj1 = *(const float4*)(rJ + ks * 32 + 4);
            float df[8];
            df[0] = fabsf(fi0.x - fj0.x); df[1] = fabsf(fi0.y - fj0.y);
            df[2] = fabsf(fi0.z - fj0.z); df[3] = fabsf(fi0.w - fj0.w);
            df[4] = fabsf(fi1.x - fj1.x); df[5] = fabsf(fi1.y - fj1.y);
            df[6] = fabsf(fi1.z - fj1.z); df[7] = fabsf(fi1.w - fj1.w);

            bfrag ah, al;
            #pragma unroll
            for (int kk = 0; kk < 8; ++kk) {
                __bf16 h = (__bf16)df[kk];
                ah[kk] = h;
                al[kk] = (__bf16)(df[kk] - (float)h);
            }
            #pragma unroll
            for (int nt = 0; nt < 4; ++nt) {
                bfrag bh = WH[((ks * 4 + nt) << 6) + lane];
                bfrag bl = WL[((ks * 4 + nt) << 6) + lane];
                acc[nt] = __builtin_amdgcn_mfma_f32_16x16x32_bf16(ah, bh, acc[nt], 0, 0, 0);
                acc[nt] = __builtin_amdgcn_mfma_f32_16x16x32_bf16(ah, bl, acc[nt], 0, 0, 0);
                acc[nt] = __builtin_amdgcn_mfma_f32_16x16x32_bf16(al, bh, acc[nt], 0, 0, 0);
            }
        }

        #pragma unroll
        for (int reg = 0; reg < 4; ++reg) {
            int e = e0 + wave * 16 + q * 4 + reg;
            if (e < EKP) {
                bf16* hp = hstore + ((size_t)b * E + e) * PH + r;
                #pragma unroll
                for (int nt = 0; nt < 4; ++nt) {
                    float v = acc[nt][reg] + b1v[nt];
                    hp[nt * 16] = __float2bfloat16(v);
                    ps[nt] += v;
                    ps2[nt] = fmaf(v, v, ps2[nt]);
                }
            }
        }
    } else {
        // ---------------- 8-neigh stencil branch ----------------
        int idx2 = blockIdx.x - nKP;
        b = idx2 % BB;
        int s = idx2 / BB;               // strip 0..15, image rows 2s,2s+1

        const int dyT[8] = {-1,-1,-1, 0, 0, 1, 1, 1};
        const int dxT[8] = {-1, 0, 1,-1, 1,-1, 0, 1};
        const int pfT[8] = {0, 961, 1953, 2914, 3906, 4898, 5859, 6851};

        int dy = dyT[wave], dx = dxT[wave];
        int y0 = dy < 0 ? 1 : 0;
        int x0 = dx < 0 ? 1 : 0;
        int ww = (dx == 0) ? 32 : 31;
        int pf = pfT[wave];
        int yA = 2 * s;

        const float* rowI[4];
        const float* rowJ[4];
        #pragma unroll
        for (int mt = 0; mt < 4; ++mt) {
            int x  = ((mt & 1) << 4) + r;
            int ni = (1 + (mt >> 1)) * 32 + x;
            int xj = x + dx; xj = xj < 0 ? 0 : (xj > 31 ? 31 : xj);
            int nj = (1 + (mt >> 1) + dy) * 32 + xj;
            rowI[mt] = &RowsBuf[ni * RSTR + q * 8];
            rowJ[mt] = &RowsBuf[nj * RSTR + q * 8];
        }

        v4f acc[4][4];
        #pragma unroll
        for (int mt = 0; mt < 4; ++mt)
            #pragma unroll
            for (int nt = 0; nt < 4; ++nt) acc[mt][nt] = (v4f)0.f;

        #pragma unroll
        for (int p = 0; p < 4; ++p) {
            __syncthreads();             // prev phase reads done (also W ready)
            const int ch0 = p * 96;
            const int nf4 = (p < 3) ? 24 : 8;
            for (int u = t; u < 128 * nf4; u += 512) {
                int node = u / nf4, c4 = u - node * nf4;
                int gy = yA - 1 + (node >> 5);
                if (gy >= 0 && gy < 32) {
                    int gn = gy * 32 + (node & 31);
                    float4 v = *(const float4*)&featT[((size_t)b * NN + gn) * CC
                                                      + ch0 + c4 * 4];
                    *(float4*)&RowsBuf[node * RSTR + c4 * 4] = v;
                }
            }
            __syncthreads();             // staging visible

            const int ksBeg = p * 3;
            const int ksEnd = (p < 3) ? ksBeg + 3 : 10;
            #pragma unroll
            for (int ks = ksBeg; ks < ksEnd; ++ks) {
                int lc = ks * 32 - ch0;
                #pragma unroll
                for (int mt = 0; mt < 4; ++mt) {
                    float4 fi0 = *(const float4*)(rowI[mt] + lc);
                    float4 fi1 = *(const float4*)(rowI[mt] + lc + 4);
                    float4 fj0 = *(const float4*)(rowJ[mt] + lc);
                    float4 fj1 = *(const float4*)(rowJ[mt] + lc + 4);
                    float df[8];
                    df[0] = fabsf(fi0.x - fj0.x); df[1] = fabsf(fi0.y - fj0.y);
                    df[2] = fabsf(fi0.z - fj0.z); df[3] = fabsf(fi0.w - fj0.w);
                    df[4] = fabsf(fi1.x - fj1.x); df[5] = fabsf(fi1.y - fj1.y);
                    df[6] = fabsf(fi1.z - fj1.z); df[7] = fabsf(fi1.w - fj1.w);

                    bfrag ah, al;
                    #pragma unroll
                    for (int kk = 0; kk < 8; ++kk) {
                        __bf16 h = (__bf16)df[kk];
                        ah[kk] = h;
                        al[kk] = (__bf16)(df[kk] - (float)h);
                    }
                    #pragma unroll
                    for (int nt = 0; nt < 4; ++nt) {
                        bfrag bh = WH[((ks * 4 + nt) << 6) + lane];
                        bfrag bl = WL[((ks * 4 + nt) << 6) + lane];
                        acc[mt][nt] = __builtin_amdgcn_mfma_f32_16x16x32_bf16(
                            ah, bh, acc[mt][nt], 0, 0, 0);
                        acc[mt][nt] = __builtin_amdgcn_mfma_f32_16x16x32_bf16(
                            ah, bl, acc[mt][nt], 0, 0, 0);
                        acc[mt][nt] = __builtin_amdgcn_mfma_f32_16x16x32_bf16(
                            al, bh, acc[mt][nt], 0, 0, 0);
                    }
                }
            }
        }

        #pragma unroll
        for (int mt = 0; mt < 4; ++mt) {
            int y = yA + (mt >> 1);
            #pragma unroll
            for (int reg = 0; reg < 4; ++reg) {
                int xi = ((mt & 1) << 4) + q * 4 + reg;
                bool valid = ((unsigned)(y + dy) < 32u) && ((unsigned)(xi + dx) < 32u);
                if (valid) {
                    int e = EKP + pf + (y - y0) * ww + (xi - x0);
                    bf16* hp = hstore + ((size_t)b * E + e) * PH + r;
                    #pragma unroll
                    for (int nt = 0; nt < 4; ++nt) {
                        float v = acc[mt][nt][reg] + b1v[nt];
                        hp[nt * 16] = __float2bfloat16(v);
                        ps[nt] += v;
                        ps2[nt] = fmaf(v, v, ps2[nt]);
                    }
                }
            }
        }
    }

    // common BN reduce (RowsBuf reused)
    __syncthreads();
    float* sS  = RowsBuf;
    float* sS2 = RowsBuf + PH;
    if (t < PH) { sS[t] = 0.f; sS2[t] = 0.f; }
    __syncthreads();
    #pragma unroll
    for (int nt = 0; nt < 4; ++nt) {
        atomicAdd(&sS[nt * 16 + r],  ps[nt]);
        atomicAdd(&sS2[nt * 16 + r], ps2[nt]);
    }
    __syncthreads();
    if (t < PH) {
        atomicAdd(&Ssum[b * PH + t],  sS[t]);
        atomicAdd(&S2sum[b * PH + t], sS2[t]);
    }
}

// -- stage 3: BN-final (in-block) + edge value + ELL scatter --------------
__global__ __launch_bounds__(256) void k_edge_val(
    const bf16* __restrict__ hstore, const float* __restrict__ Ssum,
    const float* __restrict__ S2sum, const float* __restrict__ gamma,
    const float* __restrict__ beta, const float* __restrict__ w2,
    const float* __restrict__ b2, const int* __restrict__ pairs,
    int* __restrict__ cnt, int* __restrict__ ecol, float* __restrict__ eval_,
    int E)
{
    __shared__ float ca[PH], cb[PH];
    int b = blockIdx.x % BB;
    int e = (blockIdx.x / BB) * 256 + threadIdx.x;
    if (threadIdx.x < PH) {
        int l = threadIdx.x;
        float mu = Ssum[b * PH + l] / E;
        float var = S2sum[b * PH + l] / E - mu * mu;
        float A = rsqrtf(var + 1e-5f) * gamma[l];
        ca[l] = A;
        cb[l] = beta[l] - mu * A;
    }
    __syncthreads();
    if (e >= E) return;
    const bfrag* hp = (const bfrag*)(hstore + ((size_t)b * E + e) * PH);
    float acc = 0.f;
    #pragma unroll
    for (int l8 = 0; l8 < 8; ++l8) {
        bfrag hv = hp[l8];
        #pragma unroll
        for (int c = 0; c < 8; ++c) {
            int l = l8 * 8 + c;
            float x = fmaf((float)hv[c], ca[l], cb[l]);
            x = x > 0.f ? x : 0.f;
            acc = fmaf(x, w2[l], acc);
        }
    }
    float edge = 1.f / (1.f + __expf(-(acc + b2[0])));
    const int* cp = pairs + ((size_t)b * E + e) * 2;
    int i = cp[0], j = cp[1];
    int row = b * NN + i;
    int slot = atomicAdd(&cnt[row], 1);
    if (slot < ELLW) {
        ecol[row * ELLW + slot]  = j;
        eval_[row * ELLW + slot] = edge;
    }
}

// ------ stage 4: g1 = featT @ gc1_w  (split-bf16 MFMA) -> f32 g1 ---------
__global__ __launch_bounds__(256, 2) void k_gc1(
    const float* __restrict__ featT, const __bf16* __restrict__ gwhi,
    const __bf16* __restrict__ gwlo, float* __restrict__ g1)
{
    __shared__ ushort WG[40960];   // 80 KB: hi-half, lo-half

    int t = threadIdx.x;
    int b = blockIdx.x % BB;
    int rem = blockIdx.x / BB;     // 0..31
    int half = rem & 1;
    int m0 = b * NN + (rem >> 1) * 64;

    {
        uint4* dst = (uint4*)WG;
        const uint4* sh = (const uint4*)gwhi;
        const uint4* sl = (const uint4*)gwlo;
        #pragma unroll
        for (int k = 0; k < 10; ++k) {
            int u = t + k * 256;
            int chunk = u >> 6, v = u & 63;
            int ks = chunk >> 2, ntp = chunk & 3;
            int src = (ks * 8 + half * 4 + ntp) * 64 + v;
            dst[u]        = sh[src];
            dst[2560 + u] = sl[src];
        }
    }

    int wave = t >> 6, lane = t & 63;
    int q = lane >> 4, r = lane & 15;
    const float* fp = featT + (size_t)(m0 + wave * 16 + r) * CC + q * 8;

    float fa[2][8];
    auto LOADA = [&](int ks, int buf) {
        const float4* p = (const float4*)(fp + ks * 32);
        *(float4*)&fa[buf][0] = p[0];
        *(float4*)&fa[buf][4] = p[1];
    };

    v4f acc[4];
    #pragma unroll
    for (int nt = 0; nt < 4; ++nt) acc[nt] = (v4f)0.f;

    LOADA(0, 0);
    __syncthreads();

    const bfrag* WGH = (const bfrag*)WG;
    const bfrag* WGL = (const bfrag*)(WG + 20480);

    #pragma unroll
    for (int ks = 0; ks < 10; ++ks) {
        int cur = ks & 1;
        if (ks < 9) LOADA(ks + 1, cur ^ 1);
        bfrag ah, al;
        #pragma unroll
        for (int kk = 0; kk < 8; ++kk) {
            float d = fa[cur][kk];
            __bf16 h = (__bf16)d;
            ah[kk] = h;
            al[kk] = (__bf16)(d - (float)h);
        }
        #pragma unroll
        for (int nt = 0; nt < 4; ++nt) {
            bfrag bh = WGH[((ks * 4 + nt) << 6) + lane];
            bfrag bl = WGL[((ks * 4 + nt) << 6) + lane];
            acc[nt] = __builtin_amdgcn_mfma_f32_16x16x32_bf16(ah, bh, acc[nt], 0, 0, 0);
            acc[nt] = __builtin_amdgcn_mfma_f32_16x16x32_bf16(ah, bl, acc[nt], 0, 0, 0);
            acc[nt] = __builtin_amdgcn_mfma_f32_16x16x32_bf16(al, bh, acc[nt], 0, 0, 0);
        }
    }
    #pragma unroll
    for (int nt = 0; nt < 4; ++nt) {
        #pragma unroll
        for (int reg = 0; reg < 4; ++reg) {
            int m = m0 + wave * 16 + q * 4 + reg;
            g1[(size_t)m * GH + (half * 4 + nt) * 16 + r] = acc[nt][reg];
        }
    }
}

// ------- stage 5: g2 = (leaky(adj@g1)) @ gc2_w  (1 wave/node, 2 ch/lane) -
__global__ __launch_bounds__(64) void k_spmm1(
    const float* __restrict__ g1, const int* __restrict__ cnt,
    const int* __restrict__ ecol, const float* __restrict__ eval_,
    const float* __restrict__ w2g, float* __restrict__ g2)
{
    int tid = threadIdx.x;
    int b = blockIdx.x % BB;
    int node = b * NN + blockIdx.x / BB;
    float wa = w2g[2 * tid], wb = w2g[2 * tid + 1];
    int c = cnt[node];
    const int* ec = ecol + (size_t)node * ELLW;
    const float* ev = eval_ + (size_t)node * ELLW;
    const float2* g1v = (const float2*)g1;
    float aa = 0.f, ab = 0.f;
    int s = 0;
    for (; s + 4 <= c; s += 4) {
        int j0 = ec[s], j1 = ec[s + 1], j2 = ec[s + 2], j3 = ec[s + 3];
        float v0 = ev[s], v1 = ev[s + 1], v2 = ev[s + 2], v3 = ev[s + 3];
        float2 u0 = g1v[((size_t)b * NN + j0) * 64 + tid];
        float2 u1 = g1v[((size_t)b * NN + j1) * 64 + tid];
        float2 u2 = g1v[((size_t)b * NN + j2) * 64 + tid];
        float2 u3 = g1v[((size_t)b * NN + j3) * 64 + tid];
        aa = fmaf(v0, u0.x, aa); ab = fmaf(v0, u0.y, ab);
        aa = fmaf(v1, u1.x, aa); ab = fmaf(v1, u1.y, ab);
        aa = fmaf(v2, u2.x, aa); ab = fmaf(v2, u2.y, ab);
        aa = fmaf(v3, u3.x, aa); ab = fmaf(v3, u3.y, ab);
    }
    for (; s < c; ++s) {
        float2 u = g1v[((size_t)b * NN + ec[s]) * 64 + tid];
        float v = ev[s];
        aa = fmaf(v, u.x, aa); ab = fmaf(v, u.y, ab);
    }
    float h1a = aa > 0.f ? aa : 0.2f * aa;
    float h1b = ab > 0.f ? ab : 0.2f * ab;
    float p = h1a * wa + h1b * wb;
    #pragma unroll
    for (int off = 32; off >= 1; off >>= 1) p += __shfl_down(p, off, 64);
    if (tid == 0) g2[node] = p;
}

// ------------- stage 6: out = sigmoid(adj @ g2) (1 wave/node, lane=slot) -
__global__ __launch_bounds__(64) void k_spmm2(
    const float* __restrict__ g2, const int* __restrict__ cnt,
    const int* __restrict__ ecol, const float* __restrict__ eval_,
    float* __restrict__ out)
{
    int b = blockIdx.x % BB;
    int node = b * NN + blockIdx.x / BB;
    int lane = threadIdx.x;
    int c = cnt[node];
    float p = 0.f;
    if (lane < c) {
        int j = ecol[(size_t)node * ELLW + lane];
        p = eval_[(size_t)node * ELLW + lane] * g2[b * NN + j];
    }
    #pragma unroll
    for (int off = 32; off >= 1; off >>= 1) p += __shfl_down(p, off, 64);
    if (lane == 0) out[node] = 1.f / (1.f + __expf(-p));
}

extern "C" void kernel_launch(void* const* d_in, const int* in_sizes, int n_in,
                              void* d_out, int out_size, void* d_ws, size_t ws_size,
                              hipStream_t stream)
{
    const float* search = (const float*)d_in[0];
    const float* xcorr  = (const float*)d_in[1];
    const int*   pairs  = (const int*)d_in[2];
    const float* w1     = (const float*)d_in[3];
    const float* b1     = (const float*)d_in[4];
    const float* gamma  = (const float*)d_in[5];
    const float* beta   = (const float*)d_in[6];
    const float* w2     = (const float*)d_in[7];
    const float* b2     = (const float*)d_in[8];
    const float* gc1w   = (const float*)d_in[9];
    const float* gc2w   = (const float*)d_in[10];
    float* out = (float*)d_out;

    int E   = in_sizes[2] / (BB * 2);    // 10068
    int EKP = E - NENG;                  // 2256 keypoint-clique edges
    int nb   = (E + 255) / 256;          // 40
    int nbKP = (EKP + 127) / 128;        // 18
    int nKP  = BB * nbKP;                // 288 kp blocks

    char* ws = (char*)d_ws;
    size_t off = 0;
    auto alloc = [&](size_t bytes) {
        size_t o = off;
        off += (bytes + 255) & ~(size_t)255;
        return o;
    };
    __bf16* whi   = (__bf16*)(ws + alloc(10 * 4 * 64 * 8 * 2));   // 40960 B
    __bf16* wlo   = (__bf16*)(ws + alloc(10 * 4 * 64 * 8 * 2));   // contiguous after whi
    __bf16* gwhi  = (__bf16*)(ws + alloc(10 * 8 * 64 * 8 * 2));
    __bf16* gwlo  = (__bf16*)(ws + alloc(10 * 8 * 64 * 8 * 2));
    float* featT  = (float*)(ws + alloc((size_t)BB * NN * CC * 4));
    bf16*  hstore = (bf16*)(ws + alloc((size_t)BB * E * PH * 2));
    float* Ssum   = (float*)(ws + alloc(BB * PH * 4));
    float* S2sum  = (float*)(ws + alloc(BB * PH * 4));
    int*   cnt    = (int*)(ws + alloc(BB * NN * 4));
    int*   ecol   = (int*)(ws + alloc((size_t)BB * NN * ELLW * 4));
    float* eval_  = (float*)(ws + alloc((size_t)BB * NN * ELLW * 4));
    float* g1     = (float*)(ws + alloc((size_t)BB * NN * GH * 4));
    float* g2     = (float*)(ws + alloc(BB * NN * 4));
    (void)ws_size; (void)n_in; (void)out_size;

    k_prep<<<dim3(160), dim3(256), 0, stream>>>(w1, gc1w, whi, wlo, gwhi, gwlo,
                                                cnt, Ssum, S2sum);
    k_transpose<<<dim3(BB * 320), dim3(256), 0, stream>>>(search, xcorr, featT);
    k_edge<<<dim3(nKP + BB * 16), dim3(512), 0, stream>>>(featT, pairs,
                                                          (const uint4*)whi, b1,
                                                          hstore, Ssum, S2sum,
                                                          E, EKP, nKP);
    k_edge_val<<<dim3(BB * nb), dim3(256), 0, stream>>>(hstore, Ssum, S2sum,
                                                        gamma, beta, w2, b2,
                                                        pairs, cnt, ecol, eval_, E);
    k_gc1<<<dim3(BB * 32), dim3(256), 0, stream>>>(featT, gwhi, gwlo, g1);
    k_spmm1<<<dim3(BB * NN), dim3(64), 0, stream>>>(g1, cnt, ecol, eval_, gc2w, g2);
    k_spmm2<<<dim3(BB * NN), dim3(64), 0, stream>>>(g2, cnt, ecol, eval_, out);
}

// Round 17
// 169.508 us; speedup vs baseline: 1.3477x; 1.0813x over previous
//
#include <hip/hip_runtime.h>
#include <hip/hip_bf16.h>

#define BB 16
#define NN 1024
#define CS 256
#define CX 64
#define CC 320
#define PH 64
#define GH 128
#define ELLW 64
#define NENG 7812    // 8-neigh edges per image (H=W=32)
#define ROWP 324     // padded kp row stride in floats (320 + 4)
#define RSTR 100     // ng LDS row stride in floats (96 + 4)
#define NKPH 1128    // kp half-pairs (a<y)

typedef __hip_bfloat16 bf16;
typedef __attribute__((ext_vector_type(8))) __bf16 bfrag;   // 8 bf16 = 4 VGPRs
typedef __attribute__((ext_vector_type(4))) float v4f;

// triangular decode: m in [0,1128) -> pair (a,y), a<y, kp slots 0..47
__device__ __forceinline__ void tri_decode(int m, int& a, int& y) {
    float s = sqrtf((float)(9025 - 8 * m));
    int aa = (int)((95.0f - s) * 0.5f);
    if (aa > 0 && 47 * aa - (aa * (aa - 1)) / 2 > m) --aa;
    while (47 * (aa + 1) - ((aa + 1) * aa) / 2 <= m) ++aa;
    a = aa;
    y = aa + 1 + (m - (47 * aa - (aa * (aa - 1)) / 2));
}

// ---------------- prep: pack W1 + gc1_w (hi/lo split) into B-frag order --
__global__ __launch_bounds__(256) void k_prep(
    const float* __restrict__ w1, const float* __restrict__ gc1w,
    __bf16* __restrict__ whi, __bf16* __restrict__ wlo,
    __bf16* __restrict__ gwhi, __bf16* __restrict__ gwlo,
    int* __restrict__ cnt, float* __restrict__ Ssum, float* __restrict__ S2sum)
{
    int idx = blockIdx.x * 256 + threadIdx.x;
    if (idx < 10 * 4 * 64 * 8) {          // W1: PH=64 -> 4 ntiles
        int j    = idx & 7;
        int lane = (idx >> 3) & 63;
        int nt   = (idx >> 9) & 3;
        int ks   = idx >> 11;
        int k = ks * 32 + (lane >> 4) * 8 + j;
        int n = nt * 16 + (lane & 15);
        float w = w1[k * PH + n];
        __bf16 h = (__bf16)w;
        whi[idx] = h;
        wlo[idx] = (__bf16)(w - (float)h);
    }
    if (idx < 10 * 8 * 64 * 8) {          // gc1_w: GH=128 -> 8 ntiles
        int j    = idx & 7;
        int lane = (idx >> 3) & 63;
        int nt   = (idx >> 9) & 7;
        int ks   = idx >> 12;
        int k = ks * 32 + (lane >> 4) * 8 + j;
        int n = nt * 16 + (lane & 15);
        float w = gc1w[k * GH + n];
        __bf16 h = (__bf16)w;
        gwhi[idx] = h;
        gwlo[idx] = (__bf16)(w - (float)h);
    }
    if (idx < BB * NN) cnt[idx] = 0;
    if (idx < BB * PH) { Ssum[idx] = 0.f; S2sum[idx] = 0.f; }
}

// ---------------- transpose: [B,C,N] -> featT [B,N,C] f32 ----------------
__global__ __launch_bounds__(256) void k_transpose(
    const float* __restrict__ search, const float* __restrict__ xcorr,
    float* __restrict__ featT)
{
    __shared__ float tile[32][33];
    int blk = blockIdx.x;
    int b   = blk % BB;
    int rem = blk / BB;       // 0..319
    int ct  = rem >> 5;       // 10 channel tiles
    int ntl = rem & 31;       // 32 node tiles
    int tid = threadIdx.x;
    int cl = tid >> 5, nl = tid & 31;
    const float* sb = search + (size_t)b * CS * NN;
    const float* xb = xcorr + (size_t)b * CX * NN;
    #pragma unroll
    for (int f = 0; f < 4; ++f) {
        int c = ct * 32 + cl + f * 8;
        int n = ntl * 32 + nl;
        float v = (c < CS) ? sb[(size_t)c * NN + n] : xb[(size_t)(c - CS) * NN + n];
        tile[cl + f * 8][nl] = v;
    }
    __syncthreads();
    #pragma unroll
    for (int f = 0; f < 4; ++f) {
        int nr = cl + f * 8;
        int cc = nl;
        featT[((size_t)b * NN + ntl * 32 + nr) * CC + ct * 32 + cc] = tile[cc][nr];
    }
}

// ------ stage 1 (merged, SYMMETRIC-HALVED): kp half-pairs + ng dy<=0 dirs.
//   h(i,j)=h(j,i): compute each undirected pair once, store both slots,
//   double BN contribution. All A-operands via LDS; W in LDS; bf16 hstore.
__global__ __launch_bounds__(512, 1) void k_edge(
    const float* __restrict__ featT, const int* __restrict__ pairs,
    const uint4* __restrict__ wglob, const float* __restrict__ b1,
    bf16* __restrict__ hstore, float* __restrict__ Ssum,
    float* __restrict__ S2sum, int E, int EKP, int nKP)
{
    __shared__ ushort Wsh[40960];        // 80 KB W hi||lo
    __shared__ float RowsBuf[16000];     // 64 KB (ng: 160*100; kp: 48*324)
    __shared__ int kpn[48];

    int t = threadIdx.x;
    int wave = t >> 6, lane = t & 63;
    int q = lane >> 4, r = lane & 15;

    {   // W staging: 5120 uint4, 10 per thread
        uint4* dst = (uint4*)Wsh;
        #pragma unroll
        for (int k = 0; k < 10; ++k)
            dst[t + k * 512] = wglob[t + k * 512];
    }
    const bfrag* WH = (const bfrag*)Wsh;
    const bfrag* WL = (const bfrag*)(Wsh + 20480);

    float b1v[4];
    #pragma unroll
    for (int nt = 0; nt < 4; ++nt) b1v[nt] = b1[nt * 16 + r];
    float ps[4], ps2[4];
    #pragma unroll
    for (int nt = 0; nt < 4; ++nt) { ps[nt] = 0.f; ps2[nt] = 0.f; }
    int b;

    if (blockIdx.x < nKP) {
        // ---------------- keypoint half-clique branch ----------------
        b = blockIdx.x % BB;
        int e0h = (blockIdx.x / BB) * 128;      // half-pair base
        if (t < 48) kpn[t] = pairs[((size_t)b * E + t * 47) * 2];
        __syncthreads();   // kpn + W ready

        {   // row staging: 48 rows x 80 float4
            const float4* src = (const float4*)featT;
            #pragma unroll
            for (int k = 0; k < 8; ++k) {
                int idx = t + k * 512;
                if (idx < 48 * 80) {
                    int slot = idx / 80, c4 = idx - slot * 80;
                    float4 v = src[((size_t)b * NN + kpn[slot]) * 80 + c4];
                    *(float4*)&RowsBuf[slot * ROWP + c4 * 4] = v;
                }
            }
        }

        int mA = e0h + wave * 16 + r;
        if (mA >= NKPH) mA = NKPH - 1;
        int aI, yI;
        tri_decode(mA, aI, yI);
        const float* rI = &RowsBuf[aI * ROWP + q * 8];
        const float* rJ = &RowsBuf[yI * ROWP + q * 8];

        v4f acc[4];
        #pragma unroll
        for (int nt = 0; nt < 4; ++nt) acc[nt] = (v4f)0.f;

        __syncthreads();   // rows ready

        #pragma unroll
        for (int ks = 0; ks < 10; ++ks) {
            float4 fi0 = *(const float4*)(rI + ks * 32);
            float4 fi1 = *(const float4*)(rI + ks * 32 + 4);
            float4 fj0 = *(const float4*)(rJ + ks * 32);
            float4 fj1 = *(const float4*)(rJ + ks * 32 + 4);
            float df[8];
            df[0] = fabsf(fi0.x - fj0.x); df[1] = fabsf(fi0.y - fj0.y);
            df[2] = fabsf(fi0.z - fj0.z); df[3] = fabsf(fi0.w - fj0.w);
            df[4] = fabsf(fi1.x - fj1.x); df[5] = fabsf(fi1.y - fj1.y);
            df[6] = fabsf(fi1.z - fj1.z); df[7] = fabsf(fi1.w - fj1.w);

            bfrag ah, al;
            #pragma unroll
            for (int kk = 0; kk < 8; ++kk) {
                __bf16 h = (__bf16)df[kk];
                ah[kk] = h;
                al[kk] = (__bf16)(df[kk] - (float)h);
            }
            #pragma unroll
            for (int nt = 0; nt < 4; ++nt) {
                bfrag bh = WH[((ks * 4 + nt) << 6) + lane];
                bfrag bl = WL[((ks * 4 + nt) << 6) + lane];
                acc[nt] = __builtin_amdgcn_mfma_f32_16x16x32_bf16(ah, bh, acc[nt], 0, 0, 0);
                acc[nt] = __builtin_amdgcn_mfma_f32_16x16x32_bf16(ah, bl, acc[nt], 0, 0, 0);
                acc[nt] = __builtin_amdgcn_mfma_f32_16x16x32_bf16(al, bh, acc[nt], 0, 0, 0);
            }
        }

        #pragma unroll
        for (int reg = 0; reg < 4; ++reg) {
            int mC = e0h + wave * 16 + q * 4 + reg;
            if (mC < NKPH) {
                int a, y;
                tri_decode(mC, a, y);
                int e1 = a * 47 + y - 1;    // (a,y)
                int e2 = y * 47 + a;        // (y,a)
                bf16* h1 = hstore + ((size_t)b * E + e1) * PH + r;
                bf16* h2 = hstore + ((size_t)b * E + e2) * PH + r;
                #pragma unroll
                for (int nt = 0; nt < 4; ++nt) {
                    float v = acc[nt][reg] + b1v[nt];
                    bf16 vb = __float2bfloat16(v);
                    h1[nt * 16] = vb;
                    h2[nt * 16] = vb;
                    ps[nt] += v;
                    ps2[nt] = fmaf(v, v, ps2[nt]);
                }
            }
        }
    } else {
        // ------ 8-neigh stencil branch: dirs 0..3 (dy<=0), mirror-write --
        int idx2 = blockIdx.x - nKP;
        b = idx2 % BB;
        int u = idx2 / BB;               // unit 0..7: source rows 4u..4u+3

        const int dyT[4] = {-1,-1,-1, 0};
        const int dxT[4] = {-1, 0, 1,-1};
        const int pfT8[8] = {0, 961, 1953, 2914, 3906, 4898, 5859, 6851};

        int d = wave >> 1;               // direction 0..3
        int p = wave & 1;                // row-pair within unit
        int dy = dyT[d], dx = dxT[d];
        int y0 = dy < 0 ? 1 : 0;
        int x0 = dx < 0 ? 1 : 0;
        int x0R = dx > 0 ? 1 : 0;
        int ww = (dx == 0) ? 32 : 31;
        int pfF = pfT8[d];
        int pfR = pfT8[7 - d];

        // per-lane LDS row pointers: local row lr = 1 + 2p + (mt>>1); J = lr+dy
        const float* rowI[4];
        const float* rowJ[4];
        #pragma unroll
        for (int mt = 0; mt < 4; ++mt) {
            int x  = ((mt & 1) << 4) + r;
            int lr = 1 + 2 * p + (mt >> 1);
            int ni = lr * 32 + x;
            int xj = x + dx; xj = xj < 0 ? 0 : (xj > 31 ? 31 : xj);
            int nj = (lr + dy) * 32 + xj;
            rowI[mt] = &RowsBuf[ni * RSTR + q * 8];
            rowJ[mt] = &RowsBuf[nj * RSTR + q * 8];
        }

        v4f acc[4][4];
        #pragma unroll
        for (int mt = 0; mt < 4; ++mt)
            #pragma unroll
            for (int nt = 0; nt < 4; ++nt) acc[mt][nt] = (v4f)0.f;

        #pragma unroll
        for (int ph = 0; ph < 4; ++ph) {
            __syncthreads();             // prev phase reads done (also W ready)
            const int ch0 = ph * 96;
            const int nf4 = (ph < 3) ? 24 : 8;
            for (int uu = t; uu < 160 * nf4; uu += 512) {
                int node = uu / nf4, c4 = uu - node * nf4;
                int gy = 4 * u - 1 + (node >> 5);
                if (gy >= 0) {
                    int gn = gy * 32 + (node & 31);
                    float4 v = *(const float4*)&featT[((size_t)b * NN + gn) * CC
                                                      + ch0 + c4 * 4];
                    *(float4*)&RowsBuf[node * RSTR + c4 * 4] = v;
                }
            }
            __syncthreads();             // staging visible

            const int ksBeg = ph * 3;
            const int ksEnd = (ph < 3) ? ksBeg + 3 : 10;
            #pragma unroll
            for (int ks = ksBeg; ks < ksEnd; ++ks) {
                int lc = ks * 32 - ch0;
                #pragma unroll
                for (int mt = 0; mt < 4; ++mt) {
                    float4 fi0 = *(const float4*)(rowI[mt] + lc);
                    float4 fi1 = *(const float4*)(rowI[mt] + lc + 4);
                    float4 fj0 = *(const float4*)(rowJ[mt] + lc);
                    float4 fj1 = *(const float4*)(rowJ[mt] + lc + 4);
                    float df[8];
                    df[0] = fabsf(fi0.x - fj0.x); df[1] = fabsf(fi0.y - fj0.y);
                    df[2] = fabsf(fi0.z - fj0.z); df[3] = fabsf(fi0.w - fj0.w);
                    df[4] = fabsf(fi1.x - fj1.x); df[5] = fabsf(fi1.y - fj1.y);
                    df[6] = fabsf(fi1.z - fj1.z); df[7] = fabsf(fi1.w - fj1.w);

                    bfrag ah, al;
                    #pragma unroll
                    for (int kk = 0; kk < 8; ++kk) {
                        __bf16 h = (__bf16)df[kk];
                        ah[kk] = h;
                        al[kk] = (__bf16)(df[kk] - (float)h);
                    }
                    #pragma unroll
                    for (int nt = 0; nt < 4; ++nt) {
                        bfrag bh = WH[((ks * 4 + nt) << 6) + lane];
                        bfrag bl = WL[((ks * 4 + nt) << 6) + lane];
                        acc[mt][nt] = __builtin_amdgcn_mfma_f32_16x16x32_bf16(
                            ah, bh, acc[mt][nt], 0, 0, 0);
                        acc[mt][nt] = __builtin_amdgcn_mfma_f32_16x16x32_bf16(
                            ah, bl, acc[mt][nt], 0, 0, 0);
                        acc[mt][nt] = __builtin_amdgcn_mfma_f32_16x16x32_bf16(
                            al, bh, acc[mt][nt], 0, 0, 0);
                    }
                }
            }
        }

        #pragma unroll
        for (int mt = 0; mt < 4; ++mt) {
            int y = 4 * u + 2 * p + (mt >> 1);
            #pragma unroll
            for (int reg = 0; reg < 4; ++reg) {
                int xi = ((mt & 1) << 4) + q * 4 + reg;
                int y2 = y + dy, x2 = xi + dx;
                bool valid = ((unsigned)y2 < 32u) && ((unsigned)x2 < 32u);
                if (valid) {
                    int e1 = EKP + pfF + (y - y0) * ww + (xi - x0);
                    int e2 = EKP + pfR + y2 * ww + (x2 - x0R);
                    bf16* h1 = hstore + ((size_t)b * E + e1) * PH + r;
                    bf16* h2 = hstore + ((size_t)b * E + e2) * PH + r;
                    #pragma unroll
                    for (int nt = 0; nt < 4; ++nt) {
                        float v = acc[mt][nt][reg] + b1v[nt];
                        bf16 vb = __float2bfloat16(v);
                        h1[nt * 16] = vb;
                        h2[nt * 16] = vb;
                        ps[nt] += v;
                        ps2[nt] = fmaf(v, v, ps2[nt]);
                    }
                }
            }
        }
    }

    // common BN reduce: cross-lane q-sum first, then few LDS atomics; x2 for
    // the symmetric duplicate edges.
    __syncthreads();
    float* sS  = RowsBuf;
    float* sS2 = RowsBuf + PH;
    if (t < PH) { sS[t] = 0.f; sS2[t] = 0.f; }
    __syncthreads();
    #pragma unroll
    for (int nt = 0; nt < 4; ++nt) {
        float p1 = ps[nt]  + __shfl_xor(ps[nt], 16, 64);
        p1 += __shfl_xor(p1, 32, 64);
        float p2 = ps2[nt] + __shfl_xor(ps2[nt], 16, 64);
        p2 += __shfl_xor(p2, 32, 64);
        if (lane < 16) {
            atomicAdd(&sS[nt * 16 + r],  2.0f * p1);
            atomicAdd(&sS2[nt * 16 + r], 2.0f * p2);
        }
    }
    __syncthreads();
    if (t < PH) {
        atomicAdd(&Ssum[b * PH + t],  sS[t]);
        atomicAdd(&S2sum[b * PH + t], sS2[t]);
    }
}

// -- stage 3: BN-final (in-block) + edge value + ELL scatter --------------
__global__ __launch_bounds__(256) void k_edge_val(
    const bf16* __restrict__ hstore, const float* __restrict__ Ssum,
    const float* __restrict__ S2sum, const float* __restrict__ gamma,
    const float* __restrict__ beta, const float* __restrict__ w2,
    const float* __restrict__ b2, const int* __restrict__ pairs,
    int* __restrict__ cnt, int* __restrict__ ecol, float* __restrict__ eval_,
    int E)
{
    __shared__ float ca[PH], cb[PH];
    int b = blockIdx.x % BB;
    int e = (blockIdx.x / BB) * 256 + threadIdx.x;
    if (threadIdx.x < PH) {
        int l = threadIdx.x;
        float mu = Ssum[b * PH + l] / E;
        float var = S2sum[b * PH + l] / E - mu * mu;
        float A = rsqrtf(var + 1e-5f) * gamma[l];
        ca[l] = A;
        cb[l] = beta[l] - mu * A;
    }
    __syncthreads();
    if (e >= E) return;
    const bfrag* hp = (const bfrag*)(hstore + ((size_t)b * E + e) * PH);
    float acc = 0.f;
    #pragma unroll
    for (int l8 = 0; l8 < 8; ++l8) {
        bfrag hv = hp[l8];
        #pragma unroll
        for (int c = 0; c < 8; ++c) {
            int l = l8 * 8 + c;
            float x = fmaf((float)hv[c], ca[l], cb[l]);
            x = x > 0.f ? x : 0.f;
            acc = fmaf(x, w2[l], acc);
        }
    }
    float edge = 1.f / (1.f + __expf(-(acc + b2[0])));
    const int* cp = pairs + ((size_t)b * E + e) * 2;
    int i = cp[0], j = cp[1];
    int row = b * NN + i;
    int slot = atomicAdd(&cnt[row], 1);
    if (slot < ELLW) {
        ecol[row * ELLW + slot]  = j;
        eval_[row * ELLW + slot] = edge;
    }
}

// ------ stage 4: g1 = featT @ gc1_w  (split-bf16 MFMA) -> f32 g1 ---------
__global__ __launch_bounds__(256, 2) void k_gc1(
    const float* __restrict__ featT, const __bf16* __restrict__ gwhi,
    const __bf16* __restrict__ gwlo, float* __restrict__ g1)
{
    __shared__ ushort WG[40960];   // 80 KB: hi-half, lo-half

    int t = threadIdx.x;
    int b = blockIdx.x % BB;
    int rem = blockIdx.x / BB;     // 0..31
    int half = rem & 1;
    int m0 = b * NN + (rem >> 1) * 64;

    {
        uint4* dst = (uint4*)WG;
        const uint4* sh = (const uint4*)gwhi;
        const uint4* sl = (const uint4*)gwlo;
        #pragma unroll
        for (int k = 0; k < 10; ++k) {
            int u = t + k * 256;
            int chunk = u >> 6, v = u & 63;
            int ks = chunk >> 2, ntp = chunk & 3;
            int src = (ks * 8 + half * 4 + ntp) * 64 + v;
            dst[u]        = sh[src];
            dst[2560 + u] = sl[src];
        }
    }

    int wave = t >> 6, lane = t & 63;
    int q = lane >> 4, r = lane & 15;
    const float* fp = featT + (size_t)(m0 + wave * 16 + r) * CC + q * 8;

    float fa[2][8];
    auto LOADA = [&](int ks, int buf) {
        const float4* p = (const float4*)(fp + ks * 32);
        *(float4*)&fa[buf][0] = p[0];
        *(float4*)&fa[buf][4] = p[1];
    };

    v4f acc[4];
    #pragma unroll
    for (int nt = 0; nt < 4; ++nt) acc[nt] = (v4f)0.f;

    LOADA(0, 0);
    __syncthreads();

    const bfrag* WGH = (const bfrag*)WG;
    const bfrag* WGL = (const bfrag*)(WG + 20480);

    #pragma unroll
    for (int ks = 0; ks < 10; ++ks) {
        int cur = ks & 1;
        if (ks < 9) LOADA(ks + 1, cur ^ 1);
        bfrag ah, al;
        #pragma unroll
        for (int kk = 0; kk < 8; ++kk) {
            float d = fa[cur][kk];
            __bf16 h = (__bf16)d;
            ah[kk] = h;
            al[kk] = (__bf16)(d - (float)h);
        }
        #pragma unroll
        for (int nt = 0; nt < 4; ++nt) {
            bfrag bh = WGH[((ks * 4 + nt) << 6) + lane];
            bfrag bl = WGL[((ks * 4 + nt) << 6) + lane];
            acc[nt] = __builtin_amdgcn_mfma_f32_16x16x32_bf16(ah, bh, acc[nt], 0, 0, 0);
            acc[nt] = __builtin_amdgcn_mfma_f32_16x16x32_bf16(ah, bl, acc[nt], 0, 0, 0);
            acc[nt] = __builtin_amdgcn_mfma_f32_16x16x32_bf16(al, bh, acc[nt], 0, 0, 0);
        }
    }
    #pragma unroll
    for (int nt = 0; nt < 4; ++nt) {
        #pragma unroll
        for (int reg = 0; reg < 4; ++reg) {
            int m = m0 + wave * 16 + q * 4 + reg;
            g1[(size_t)m * GH + (half * 4 + nt) * 16 + r] = acc[nt][reg];
        }
    }
}

// ------- stage 5: g2 = (leaky(adj@g1)) @ gc2_w  (1 wave/node, 2 ch/lane) -
__global__ __launch_bounds__(64) void k_spmm1(
    const float* __restrict__ g1, const int* __restrict__ cnt,
    const int* __restrict__ ecol, const float* __restrict__ eval_,
    const float* __restrict__ w2g, float* __restrict__ g2)
{
    int tid = threadIdx.x;
    int b = blockIdx.x % BB;
    int node = b * NN + blockIdx.x / BB;
    float wa = w2g[2 * tid], wb = w2g[2 * tid + 1];
    int c = cnt[node];
    const int* ec = ecol + (size_t)node * ELLW;
    const float* ev = eval_ + (size_t)node * ELLW;
    const float2* g1v = (const float2*)g1;
    float aa = 0.f, ab = 0.f;
    int s = 0;
    for (; s + 4 <= c; s += 4) {
        int j0 = ec[s], j1 = ec[s + 1], j2 = ec[s + 2], j3 = ec[s + 3];
        float v0 = ev[s], v1 = ev[s + 1], v2 = ev[s + 2], v3 = ev[s + 3];
        float2 u0 = g1v[((size_t)b * NN + j0) * 64 + tid];
        float2 u1 = g1v[((size_t)b * NN + j1) * 64 + tid];
        float2 u2 = g1v[((size_t)b * NN + j2) * 64 + tid];
        float2 u3 = g1v[((size_t)b * NN + j3) * 64 + tid];
        aa = fmaf(v0, u0.x, aa); ab = fmaf(v0, u0.y, ab);
        aa = fmaf(v1, u1.x, aa); ab = fmaf(v1, u1.y, ab);
        aa = fmaf(v2, u2.x, aa); ab = fmaf(v2, u2.y, ab);
        aa = fmaf(v3, u3.x, aa); ab = fmaf(v3, u3.y, ab);
    }
    for (; s < c; ++s) {
        float2 u = g1v[((size_t)b * NN + ec[s]) * 64 + tid];
        float v = ev[s];
        aa = fmaf(v, u.x, aa); ab = fmaf(v, u.y, ab);
    }
    float h1a = aa > 0.f ? aa : 0.2f * aa;
    float h1b = ab > 0.f ? ab : 0.2f * ab;
    float p = h1a * wa + h1b * wb;
    #pragma unroll
    for (int off = 32; off >= 1; off >>= 1) p += __shfl_down(p, off, 64);
    if (tid == 0) g2[node] = p;
}

// ------------- stage 6: out = sigmoid(adj @ g2) (1 wave/node, lane=slot) -
__global__ __launch_bounds__(64) void k_spmm2(
    const float* __restrict__ g2, const int* __restrict__ cnt,
    const int* __restrict__ ecol, const float* __restrict__ eval_,
    float* __restrict__ out)
{
    int b = blockIdx.x % BB;
    int node = b * NN + blockIdx.x / BB;
    int lane = threadIdx.x;
    int c = cnt[node];
    float p = 0.f;
    if (lane < c) {
        int j = ecol[(size_t)node * ELLW + lane];
        p = eval_[(size_t)node * ELLW + lane] * g2[b * NN + j];
    }
    #pragma unroll
    for (int off = 32; off >= 1; off >>= 1) p += __shfl_down(p, off, 64);
    if (lane == 0) out[node] = 1.f / (1.f + __expf(-p));
}

extern "C" void kernel_launch(void* const* d_in, const int* in_sizes, int n_in,
                              void* d_out, int out_size, void* d_ws, size_t ws_size,
                              hipStream_t stream)
{
    const float* search = (const float*)d_in[0];
    const float* xcorr  = (const float*)d_in[1];
    const int*   pairs  = (const int*)d_in[2];
    const float* w1     = (const float*)d_in[3];
    const float* b1     = (const float*)d_in[4];
    const float* gamma  = (const float*)d_in[5];
    const float* beta   = (const float*)d_in[6];
    const float* w2     = (const float*)d_in[7];
    const float* b2     = (const float*)d_in[8];
    const float* gc1w   = (const float*)d_in[9];
    const float* gc2w   = (const float*)d_in[10];
    float* out = (float*)d_out;

    int E   = in_sizes[2] / (BB * 2);    // 10068
    int EKP = E - NENG;                  // 2256 keypoint-clique edges
    int nb   = (E + 255) / 256;          // 40
    int nbKP = (NKPH + 127) / 128;       // 9 half-pair tiles
    int nKP  = BB * nbKP;                // 144 kp blocks

    char* ws = (char*)d_ws;
    size_t off = 0;
    auto alloc = [&](size_t bytes) {
        size_t o = off;
        off += (bytes + 255) & ~(size_t)255;
        return o;
    };
    __bf16* whi   = (__bf16*)(ws + alloc(10 * 4 * 64 * 8 * 2));   // 40960 B
    __bf16* wlo   = (__bf16*)(ws + alloc(10 * 4 * 64 * 8 * 2));   // contiguous after whi
    __bf16* gwhi  = (__bf16*)(ws + alloc(10 * 8 * 64 * 8 * 2));
    __bf16* gwlo  = (__bf16*)(ws + alloc(10 * 8 * 64 * 8 * 2));
    float* featT  = (float*)(ws + alloc((size_t)BB * NN * CC * 4));
    bf16*  hstore = (bf16*)(ws + alloc((size_t)BB * E * PH * 2));
    float* Ssum   = (float*)(ws + alloc(BB * PH * 4));
    float* S2sum  = (float*)(ws + alloc(BB * PH * 4));
    int*   cnt    = (int*)(ws + alloc(BB * NN * 4));
    int*   ecol   = (int*)(ws + alloc((size_t)BB * NN * ELLW * 4));
    float* eval_  = (float*)(ws + alloc((size_t)BB * NN * ELLW * 4));
    float* g1     = (float*)(ws + alloc((size_t)BB * NN * GH * 4));
    float* g2     = (float*)(ws + alloc(BB * NN * 4));
    (void)ws_size; (void)n_in; (void)out_size;

    k_prep<<<dim3(160), dim3(256), 0, stream>>>(w1, gc1w, whi, wlo, gwhi, gwlo,
                                                cnt, Ssum, S2sum);
    k_transpose<<<dim3(BB * 320), dim3(256), 0, stream>>>(search, xcorr, featT);
    k_edge<<<dim3(nKP + BB * 8), dim3(512), 0, stream>>>(featT, pairs,
                                                         (const uint4*)whi, b1,
                                                         hstore, Ssum, S2sum,
                                                         E, EKP, nKP);
    k_edge_val<<<dim3(BB * nb), dim3(256), 0, stream>>>(hstore, Ssum, S2sum,
                                                        gamma, beta, w2, b2,
                                                        pairs, cnt, ecol, eval_, E);
    k_gc1<<<dim3(BB * 32), dim3(256), 0, stream>>>(featT, gwhi, gwlo, g1);
    k_spmm1<<<dim3(BB * NN), dim3(64), 0, stream>>>(g1, cnt, ecol, eval_, gc2w, g2);
    k_spmm2<<<dim3(BB * NN), dim3(64), 0, stream>>>(g2, cnt, ecol, eval_, out);
}

// Round 18
// 158.586 us; speedup vs baseline: 1.4405x; 1.0689x over previous
//
#include <hip/hip_runtime.h>
#include <hip/hip_bf16.h>

#define BB 16
#define NN 1024
#define CS 256
#define CX 64
#define CC 320
#define PH 64
#define GH 128
#define ELLW 64
#define NENG 7812    // 8-neigh edges per image (H=W=32)
#define ROWP 324     // padded kp row stride in floats (320 + 4)
#define RSTR 100     // ng LDS row stride in floats (96 + 4)
#define NKPH 1128    // kp half-pairs (a<y)

typedef __hip_bfloat16 bf16;
typedef __attribute__((ext_vector_type(8))) __bf16 bfrag;   // 8 bf16 = 4 VGPRs
typedef __attribute__((ext_vector_type(4))) float v4f;

// triangular decode: m in [0,1128) -> pair (a,y), a<y, kp slots 0..47
__device__ __forceinline__ void tri_decode(int m, int& a, int& y) {
    float s = sqrtf((float)(9025 - 8 * m));
    int aa = (int)((95.0f - s) * 0.5f);
    if (aa > 0 && 47 * aa - (aa * (aa - 1)) / 2 > m) --aa;
    while (47 * (aa + 1) - ((aa + 1) * aa) / 2 <= m) ++aa;
    a = aa;
    y = aa + 1 + (m - (47 * aa - (aa * (aa - 1)) / 2));
}

// ---------------- prep: pack W1 + gc1_w (hi/lo split) into B-frag order --
__global__ __launch_bounds__(256) void k_prep(
    const float* __restrict__ w1, const float* __restrict__ gc1w,
    __bf16* __restrict__ whi, __bf16* __restrict__ wlo,
    __bf16* __restrict__ gwhi, __bf16* __restrict__ gwlo,
    int* __restrict__ cnt, float* __restrict__ Ssum, float* __restrict__ S2sum)
{
    int idx = blockIdx.x * 256 + threadIdx.x;
    if (idx < 10 * 4 * 64 * 8) {          // W1: PH=64 -> 4 ntiles
        int j    = idx & 7;
        int lane = (idx >> 3) & 63;
        int nt   = (idx >> 9) & 3;
        int ks   = idx >> 11;
        int k = ks * 32 + (lane >> 4) * 8 + j;
        int n = nt * 16 + (lane & 15);
        float w = w1[k * PH + n];
        __bf16 h = (__bf16)w;
        whi[idx] = h;
        wlo[idx] = (__bf16)(w - (float)h);
    }
    if (idx < 10 * 8 * 64 * 8) {          // gc1_w: GH=128 -> 8 ntiles
        int j    = idx & 7;
        int lane = (idx >> 3) & 63;
        int nt   = (idx >> 9) & 7;
        int ks   = idx >> 12;
        int k = ks * 32 + (lane >> 4) * 8 + j;
        int n = nt * 16 + (lane & 15);
        float w = gc1w[k * GH + n];
        __bf16 h = (__bf16)w;
        gwhi[idx] = h;
        gwlo[idx] = (__bf16)(w - (float)h);
    }
    if (idx < BB * NN) cnt[idx] = 0;
    if (idx < BB * PH) { Ssum[idx] = 0.f; S2sum[idx] = 0.f; }
}

// ---------------- transpose: [B,C,N] -> featT [B,N,C] f32 ----------------
__global__ __launch_bounds__(256) void k_transpose(
    const float* __restrict__ search, const float* __restrict__ xcorr,
    float* __restrict__ featT)
{
    __shared__ float tile[32][33];
    int blk = blockIdx.x;
    int b   = blk % BB;
    int rem = blk / BB;       // 0..319
    int ct  = rem >> 5;       // 10 channel tiles
    int ntl = rem & 31;       // 32 node tiles
    int tid = threadIdx.x;
    int cl = tid >> 5, nl = tid & 31;
    const float* sb = search + (size_t)b * CS * NN;
    const float* xb = xcorr + (size_t)b * CX * NN;
    #pragma unroll
    for (int f = 0; f < 4; ++f) {
        int c = ct * 32 + cl + f * 8;
        int n = ntl * 32 + nl;
        float v = (c < CS) ? sb[(size_t)c * NN + n] : xb[(size_t)(c - CS) * NN + n];
        tile[cl + f * 8][nl] = v;
    }
    __syncthreads();
    #pragma unroll
    for (int f = 0; f < 4; ++f) {
        int nr = cl + f * 8;
        int cc = nl;
        featT[((size_t)b * NN + ntl * 32 + nr) * CC + ct * 32 + cc] = tile[cc][nr];
    }
}

// ------ stage 1 (merged, SYMMETRIC-HALVED): ng 2-row strips FIRST (heavy,
//   fill all CUs in round 1), then kp half-pair blocks backfill.
__global__ __launch_bounds__(512, 1) void k_edge(
    const float* __restrict__ featT, const int* __restrict__ pairs,
    const uint4* __restrict__ wglob, const float* __restrict__ b1,
    bf16* __restrict__ hstore, float* __restrict__ Ssum,
    float* __restrict__ S2sum, int E, int EKP, int nNG)
{
    __shared__ ushort Wsh[40960];        // 80 KB W hi||lo
    __shared__ float RowsBuf[16000];     // 64 KB (kp: 48*324; ng: 96*100)
    __shared__ int kpn[48];

    int t = threadIdx.x;
    int wave = t >> 6, lane = t & 63;
    int q = lane >> 4, r = lane & 15;

    {   // W staging: 5120 uint4, 10 per thread
        uint4* dst = (uint4*)Wsh;
        #pragma unroll
        for (int k = 0; k < 10; ++k)
            dst[t + k * 512] = wglob[t + k * 512];
    }
    const bfrag* WH = (const bfrag*)Wsh;
    const bfrag* WL = (const bfrag*)(Wsh + 20480);

    float b1v[4];
    #pragma unroll
    for (int nt = 0; nt < 4; ++nt) b1v[nt] = b1[nt * 16 + r];
    float ps[4], ps2[4];
    #pragma unroll
    for (int nt = 0; nt < 4; ++nt) { ps[nt] = 0.f; ps2[nt] = 0.f; }
    int b;

    if (blockIdx.x < nNG) {
        // ------ 8-neigh stencil branch: 2-row strip, dirs 0..3 (dy<=0) ---
        b = blockIdx.x % BB;
        int s = blockIdx.x / BB;         // strip 0..15, source rows 2s,2s+1

        const int dyT[4] = {-1,-1,-1, 0};
        const int dxT[4] = {-1, 0, 1,-1};
        const int pfT8[8] = {0, 961, 1953, 2914, 3906, 4898, 5859, 6851};

        int d = wave >> 1;               // direction 0..3
        int p = wave & 1;                // source row within strip
        int dy = dyT[d], dx = dxT[d];
        int y0 = dy < 0 ? 1 : 0;
        int x0 = dx < 0 ? 1 : 0;
        int x0R = dx > 0 ? 1 : 0;
        int ww = (dx == 0) ? 32 : 31;
        int pfF = pfT8[d];
        int pfR = pfT8[7 - d];
        int y = 2 * s + p;

        // local rows staged: gy = 2s-1 + lr, lr in 0..2; source row lr = 1+p
        const float* rowI[2];
        const float* rowJ[2];
        #pragma unroll
        for (int mt = 0; mt < 2; ++mt) {
            int x  = (mt << 4) + r;
            int lr = 1 + p;
            int ni = lr * 32 + x;
            int xj = x + dx; xj = xj < 0 ? 0 : (xj > 31 ? 31 : xj);
            int nj = (lr + dy) * 32 + xj;
            rowI[mt] = &RowsBuf[ni * RSTR + q * 8];
            rowJ[mt] = &RowsBuf[nj * RSTR + q * 8];
        }

        v4f acc[2][4];
        #pragma unroll
        for (int mt = 0; mt < 2; ++mt)
            #pragma unroll
            for (int nt = 0; nt < 4; ++nt) acc[mt][nt] = (v4f)0.f;

        #pragma unroll
        for (int ph = 0; ph < 4; ++ph) {
            __syncthreads();             // prev phase reads done (also W ready)
            const int ch0 = ph * 96;
            const int nf4 = (ph < 3) ? 24 : 8;
            for (int uu = t; uu < 96 * nf4; uu += 512) {
                int node = uu / nf4, c4 = uu - node * nf4;
                int gy = 2 * s - 1 + (node >> 5);
                if (gy >= 0) {
                    int gn = gy * 32 + (node & 31);
                    float4 v = *(const float4*)&featT[((size_t)b * NN + gn) * CC
                                                      + ch0 + c4 * 4];
                    *(float4*)&RowsBuf[node * RSTR + c4 * 4] = v;
                }
            }
            __syncthreads();             // staging visible

            const int ksBeg = ph * 3;
            const int ksEnd = (ph < 3) ? ksBeg + 3 : 10;
            #pragma unroll
            for (int ks = ksBeg; ks < ksEnd; ++ks) {
                int lc = ks * 32 - ch0;
                #pragma unroll
                for (int mt = 0; mt < 2; ++mt) {
                    float4 fi0 = *(const float4*)(rowI[mt] + lc);
                    float4 fi1 = *(const float4*)(rowI[mt] + lc + 4);
                    float4 fj0 = *(const float4*)(rowJ[mt] + lc);
                    float4 fj1 = *(const float4*)(rowJ[mt] + lc + 4);
                    float df[8];
                    df[0] = fabsf(fi0.x - fj0.x); df[1] = fabsf(fi0.y - fj0.y);
                    df[2] = fabsf(fi0.z - fj0.z); df[3] = fabsf(fi0.w - fj0.w);
                    df[4] = fabsf(fi1.x - fj1.x); df[5] = fabsf(fi1.y - fj1.y);
                    df[6] = fabsf(fi1.z - fj1.z); df[7] = fabsf(fi1.w - fj1.w);

                    bfrag ah, al;
                    #pragma unroll
                    for (int kk = 0; kk < 8; ++kk) {
                        __bf16 h = (__bf16)df[kk];
                        ah[kk] = h;
                        al[kk] = (__bf16)(df[kk] - (float)h);
                    }
                    #pragma unroll
                    for (int nt = 0; nt < 4; ++nt) {
                        bfrag bh = WH[((ks * 4 + nt) << 6) + lane];
                        bfrag bl = WL[((ks * 4 + nt) << 6) + lane];
                        acc[mt][nt] = __builtin_amdgcn_mfma_f32_16x16x32_bf16(
                            ah, bh, acc[mt][nt], 0, 0, 0);
                        acc[mt][nt] = __builtin_amdgcn_mfma_f32_16x16x32_bf16(
                            ah, bl, acc[mt][nt], 0, 0, 0);
                        acc[mt][nt] = __builtin_amdgcn_mfma_f32_16x16x32_bf16(
                            al, bh, acc[mt][nt], 0, 0, 0);
                    }
                }
            }
        }

        #pragma unroll
        for (int mt = 0; mt < 2; ++mt) {
            #pragma unroll
            for (int reg = 0; reg < 4; ++reg) {
                int xi = (mt << 4) + q * 4 + reg;
                int y2 = y + dy, x2 = xi + dx;
                bool valid = ((unsigned)y2 < 32u) && ((unsigned)x2 < 32u);
                if (valid) {
                    int e1 = EKP + pfF + (y - y0) * ww + (xi - x0);
                    int e2 = EKP + pfR + y2 * ww + (x2 - x0R);
                    bf16* h1 = hstore + ((size_t)b * E + e1) * PH + r;
                    bf16* h2 = hstore + ((size_t)b * E + e2) * PH + r;
                    #pragma unroll
                    for (int nt = 0; nt < 4; ++nt) {
                        float v = acc[mt][nt][reg] + b1v[nt];
                        bf16 vb = __float2bfloat16(v);
                        h1[nt * 16] = vb;
                        h2[nt * 16] = vb;
                        ps[nt] += v;
                        ps2[nt] = fmaf(v, v, ps2[nt]);
                    }
                }
            }
        }
    } else {
        // ---------------- keypoint half-clique branch ----------------
        int idx2 = blockIdx.x - nNG;
        b = idx2 % BB;
        int e0h = (idx2 / BB) * 128;            // half-pair base
        if (t < 48) kpn[t] = pairs[((size_t)b * E + t * 47) * 2];
        __syncthreads();   // kpn + W ready

        {   // row staging: 48 rows x 80 float4
            const float4* src = (const float4*)featT;
            #pragma unroll
            for (int k = 0; k < 8; ++k) {
                int idx = t + k * 512;
                if (idx < 48 * 80) {
                    int slot = idx / 80, c4 = idx - slot * 80;
                    float4 v = src[((size_t)b * NN + kpn[slot]) * 80 + c4];
                    *(float4*)&RowsBuf[slot * ROWP + c4 * 4] = v;
                }
            }
        }

        int mA = e0h + wave * 16 + r;
        if (mA >= NKPH) mA = NKPH - 1;
        int aI, yI;
        tri_decode(mA, aI, yI);
        const float* rI = &RowsBuf[aI * ROWP + q * 8];
        const float* rJ = &RowsBuf[yI * ROWP + q * 8];

        v4f acc[4];
        #pragma unroll
        for (int nt = 0; nt < 4; ++nt) acc[nt] = (v4f)0.f;

        __syncthreads();   // rows ready

        #pragma unroll
        for (int ks = 0; ks < 10; ++ks) {
            float4 fi0 = *(const float4*)(rI + ks * 32);
            float4 fi1 = *(const float4*)(rI + ks * 32 + 4);
            float4 fj0 = *(const float4*)(rJ + ks * 32);
            float4 fj1 = *(const float4*)(rJ + ks * 32 + 4);
            float df[8];
            df[0] = fabsf(fi0.x - fj0.x); df[1] = fabsf(fi0.y - fj0.y);
            df[2] = fabsf(fi0.z - fj0.z); df[3] = fabsf(fi0.w - fj0.w);
            df[4] = fabsf(fi1.x - fj1.x); df[5] = fabsf(fi1.y - fj1.y);
            df[6] = fabsf(fi1.z - fj1.z); df[7] = fabsf(fi1.w - fj1.w);

            bfrag ah, al;
            #pragma unroll
            for (int kk = 0; kk < 8; ++kk) {
                __bf16 h = (__bf16)df[kk];
                ah[kk] = h;
                al[kk] = (__bf16)(df[kk] - (float)h);
            }
            #pragma unroll
            for (int nt = 0; nt < 4; ++nt) {
                bfrag bh = WH[((ks * 4 + nt) << 6) + lane];
                bfrag bl = WL[((ks * 4 + nt) << 6) + lane];
                acc[nt] = __builtin_amdgcn_mfma_f32_16x16x32_bf16(ah, bh, acc[nt], 0, 0, 0);
                acc[nt] = __builtin_amdgcn_mfma_f32_16x16x32_bf16(ah, bl, acc[nt], 0, 0, 0);
                acc[nt] = __builtin_amdgcn_mfma_f32_16x16x32_bf16(al, bh, acc[nt], 0, 0, 0);
            }
        }

        #pragma unroll
        for (int reg = 0; reg < 4; ++reg) {
            int mC = e0h + wave * 16 + q * 4 + reg;
            if (mC < NKPH) {
                int a, y;
                tri_decode(mC, a, y);
                int e1 = a * 47 + y - 1;    // (a,y)
                int e2 = y * 47 + a;        // (y,a)
                bf16* h1 = hstore + ((size_t)b * E + e1) * PH + r;
                bf16* h2 = hstore + ((size_t)b * E + e2) * PH + r;
                #pragma unroll
                for (int nt = 0; nt < 4; ++nt) {
                    float v = acc[nt][reg] + b1v[nt];
                    bf16 vb = __float2bfloat16(v);
                    h1[nt * 16] = vb;
                    h2[nt * 16] = vb;
                    ps[nt] += v;
                    ps2[nt] = fmaf(v, v, ps2[nt]);
                }
            }
        }
    }

    // common BN reduce: cross-lane q-sum, few LDS atomics; x2 for symmetric
    // duplicate edges.
    __syncthreads();
    float* sS  = RowsBuf;
    float* sS2 = RowsBuf + PH;
    if (t < PH) { sS[t] = 0.f; sS2[t] = 0.f; }
    __syncthreads();
    #pragma unroll
    for (int nt = 0; nt < 4; ++nt) {
        float p1 = ps[nt]  + __shfl_xor(ps[nt], 16, 64);
        p1 += __shfl_xor(p1, 32, 64);
        float p2 = ps2[nt] + __shfl_xor(ps2[nt], 16, 64);
        p2 += __shfl_xor(p2, 32, 64);
        if (lane < 16) {
            atomicAdd(&sS[nt * 16 + r],  2.0f * p1);
            atomicAdd(&sS2[nt * 16 + r], 2.0f * p2);
        }
    }
    __syncthreads();
    if (t < PH) {
        atomicAdd(&Ssum[b * PH + t],  sS[t]);
        atomicAdd(&S2sum[b * PH + t], sS2[t]);
    }
}

// -- stage 3: BN-final (in-block) + edge value + ELL scatter --------------
__global__ __launch_bounds__(256) void k_edge_val(
    const bf16* __restrict__ hstore, const float* __restrict__ Ssum,
    const float* __restrict__ S2sum, const float* __restrict__ gamma,
    const float* __restrict__ beta, const float* __restrict__ w2,
    const float* __restrict__ b2, const int* __restrict__ pairs,
    int* __restrict__ cnt, int* __restrict__ ecol, float* __restrict__ eval_,
    int E)
{
    __shared__ float ca[PH], cb[PH];
    int b = blockIdx.x % BB;
    int e = (blockIdx.x / BB) * 256 + threadIdx.x;
    if (threadIdx.x < PH) {
        int l = threadIdx.x;
        float mu = Ssum[b * PH + l] / E;
        float var = S2sum[b * PH + l] / E - mu * mu;
        float A = rsqrtf(var + 1e-5f) * gamma[l];
        ca[l] = A;
        cb[l] = beta[l] - mu * A;
    }
    __syncthreads();
    if (e >= E) return;
    const bfrag* hp = (const bfrag*)(hstore + ((size_t)b * E + e) * PH);
    float acc = 0.f;
    #pragma unroll
    for (int l8 = 0; l8 < 8; ++l8) {
        bfrag hv = hp[l8];
        #pragma unroll
        for (int c = 0; c < 8; ++c) {
            int l = l8 * 8 + c;
            float x = fmaf((float)hv[c], ca[l], cb[l]);
            x = x > 0.f ? x : 0.f;
            acc = fmaf(x, w2[l], acc);
        }
    }
    float edge = 1.f / (1.f + __expf(-(acc + b2[0])));
    const int* cp = pairs + ((size_t)b * E + e) * 2;
    int i = cp[0], j = cp[1];
    int row = b * NN + i;
    int slot = atomicAdd(&cnt[row], 1);
    if (slot < ELLW) {
        ecol[row * ELLW + slot]  = j;
        eval_[row * ELLW + slot] = edge;
    }
}

// ------ stage 4: g1 = featT @ gc1_w  (split-bf16 MFMA) -> f32 g1 ---------
__global__ __launch_bounds__(256, 2) void k_gc1(
    const float* __restrict__ featT, const __bf16* __restrict__ gwhi,
    const __bf16* __restrict__ gwlo, float* __restrict__ g1)
{
    __shared__ ushort WG[40960];   // 80 KB: hi-half, lo-half

    int t = threadIdx.x;
    int b = blockIdx.x % BB;
    int rem = blockIdx.x / BB;     // 0..31
    int half = rem & 1;
    int m0 = b * NN + (rem >> 1) * 64;

    {
        uint4* dst = (uint4*)WG;
        const uint4* sh = (const uint4*)gwhi;
        const uint4* sl = (const uint4*)gwlo;
        #pragma unroll
        for (int k = 0; k < 10; ++k) {
            int u = t + k * 256;
            int chunk = u >> 6, v = u & 63;
            int ks = chunk >> 2, ntp = chunk & 3;
            int src = (ks * 8 + half * 4 + ntp) * 64 + v;
            dst[u]        = sh[src];
            dst[2560 + u] = sl[src];
        }
    }

    int wave = t >> 6, lane = t & 63;
    int q = lane >> 4, r = lane & 15;
    const float* fp = featT + (size_t)(m0 + wave * 16 + r) * CC + q * 8;

    float fa[2][8];
    auto LOADA = [&](int ks, int buf) {
        const float4* p = (const float4*)(fp + ks * 32);
        *(float4*)&fa[buf][0] = p[0];
        *(float4*)&fa[buf][4] = p[1];
    };

    v4f acc[4];
    #pragma unroll
    for (int nt = 0; nt < 4; ++nt) acc[nt] = (v4f)0.f;

    LOADA(0, 0);
    __syncthreads();

    const bfrag* WGH = (const bfrag*)WG;
    const bfrag* WGL = (const bfrag*)(WG + 20480);

    #pragma unroll
    for (int ks = 0; ks < 10; ++ks) {
        int cur = ks & 1;
        if (ks < 9) LOADA(ks + 1, cur ^ 1);
        bfrag ah, al;
        #pragma unroll
        for (int kk = 0; kk < 8; ++kk) {
            float d = fa[cur][kk];
            __bf16 h = (__bf16)d;
            ah[kk] = h;
            al[kk] = (__bf16)(d - (float)h);
        }
        #pragma unroll
        for (int nt = 0; nt < 4; ++nt) {
            bfrag bh = WGH[((ks * 4 + nt) << 6) + lane];
            bfrag bl = WGL[((ks * 4 + nt) << 6) + lane];
            acc[nt] = __builtin_amdgcn_mfma_f32_16x16x32_bf16(ah, bh, acc[nt], 0, 0, 0);
            acc[nt] = __builtin_amdgcn_mfma_f32_16x16x32_bf16(ah, bl, acc[nt], 0, 0, 0);
            acc[nt] = __builtin_amdgcn_mfma_f32_16x16x32_bf16(al, bh, acc[nt], 0, 0, 0);
        }
    }
    #pragma unroll
    for (int nt = 0; nt < 4; ++nt) {
        #pragma unroll
        for (int reg = 0; reg < 4; ++reg) {
            int m = m0 + wave * 16 + q * 4 + reg;
            g1[(size_t)m * GH + (half * 4 + nt) * 16 + r] = acc[nt][reg];
        }
    }
}

// ------- stage 5: g2 = (leaky(adj@g1)) @ gc2_w  (1 wave/node, 2 ch/lane) -
__global__ __launch_bounds__(64) void k_spmm1(
    const float* __restrict__ g1, const int* __restrict__ cnt,
    const int* __restrict__ ecol, const float* __restrict__ eval_,
    const float* __restrict__ w2g, float* __restrict__ g2)
{
    int tid = threadIdx.x;
    int b = blockIdx.x % BB;
    int node = b * NN + blockIdx.x / BB;
    float wa = w2g[2 * tid], wb = w2g[2 * tid + 1];
    int c = cnt[node];
    const int* ec = ecol + (size_t)node * ELLW;
    const float* ev = eval_ + (size_t)node * ELLW;
    const float2* g1v = (const float2*)g1;
    float aa = 0.f, ab = 0.f;
    int s = 0;
    for (; s + 4 <= c; s += 4) {
        int j0 = ec[s], j1 = ec[s + 1], j2 = ec[s + 2], j3 = ec[s + 3];
        float v0 = ev[s], v1 = ev[s + 1], v2 = ev[s + 2], v3 = ev[s + 3];
        float2 u0 = g1v[((size_t)b * NN + j0) * 64 + tid];
        float2 u1 = g1v[((size_t)b * NN + j1) * 64 + tid];
        float2 u2 = g1v[((size_t)b * NN + j2) * 64 + tid];
        float2 u3 = g1v[((size_t)b * NN + j3) * 64 + tid];
        aa = fmaf(v0, u0.x, aa); ab = fmaf(v0, u0.y, ab);
        aa = fmaf(v1, u1.x, aa); ab = fmaf(v1, u1.y, ab);
        aa = fmaf(v2, u2.x, aa); ab = fmaf(v2, u2.y, ab);
        aa = fmaf(v3, u3.x, aa); ab = fmaf(v3, u3.y, ab);
    }
    for (; s < c; ++s) {
        float2 u = g1v[((size_t)b * NN + ec[s]) * 64 + tid];
        float v = ev[s];
        aa = fmaf(v, u.x, aa); ab = fmaf(v, u.y, ab);
    }
    float h1a = aa > 0.f ? aa : 0.2f * aa;
    float h1b = ab > 0.f ? ab : 0.2f * ab;
    float p = h1a * wa + h1b * wb;
    #pragma unroll
    for (int off = 32; off >= 1; off >>= 1) p += __shfl_down(p, off, 64);
    if (tid == 0) g2[node] = p;
}

// ------------- stage 6: out = sigmoid(adj @ g2) (1 wave/node, lane=slot) -
__global__ __launch_bounds__(64) void k_spmm2(
    const float* __restrict__ g2, const int* __restrict__ cnt,
    const int* __restrict__ ecol, const float* __restrict__ eval_,
    float* __restrict__ out)
{
    int b = blockIdx.x % BB;
    int node = b * NN + blockIdx.x / BB;
    int lane = threadIdx.x;
    int c = cnt[node];
    float p = 0.f;
    if (lane < c) {
        int j = ecol[(size_t)node * ELLW + lane];
        p = eval_[(size_t)node * ELLW + lane] * g2[b * NN + j];
    }
    #pragma unroll
    for (int off = 32; off >= 1; off >>= 1) p += __shfl_down(p, off, 64);
    if (lane == 0) out[node] = 1.f / (1.f + __expf(-p));
}

extern "C" void kernel_launch(void* const* d_in, const int* in_sizes, int n_in,
                              void* d_out, int out_size, void* d_ws, size_t ws_size,
                              hipStream_t stream)
{
    const float* search = (const float*)d_in[0];
    const float* xcorr  = (const float*)d_in[1];
    const int*   pairs  = (const int*)d_in[2];
    const float* w1     = (const float*)d_in[3];
    const float* b1     = (const float*)d_in[4];
    const float* gamma  = (const float*)d_in[5];
    const float* beta   = (const float*)d_in[6];
    const float* w2     = (const float*)d_in[7];
    const float* b2     = (const float*)d_in[8];
    const float* gc1w   = (const float*)d_in[9];
    const float* gc2w   = (const float*)d_in[10];
    float* out = (float*)d_out;

    int E   = in_sizes[2] / (BB * 2);    // 10068
    int EKP = E - NENG;                  // 2256 keypoint-clique edges
    int nb   = (E + 255) / 256;          // 40
    int nbKP = (NKPH + 127) / 128;       // 9 half-pair tiles
    int nNG  = BB * 16;                  // 256 ng strip blocks (dispatched first)

    char* ws = (char*)d_ws;
    size_t off = 0;
    auto alloc = [&](size_t bytes) {
        size_t o = off;
        off += (bytes + 255) & ~(size_t)255;
        return o;
    };
    __bf16* whi   = (__bf16*)(ws + alloc(10 * 4 * 64 * 8 * 2));   // 40960 B
    __bf16* wlo   = (__bf16*)(ws + alloc(10 * 4 * 64 * 8 * 2));   // contiguous after whi
    __bf16* gwhi  = (__bf16*)(ws + alloc(10 * 8 * 64 * 8 * 2));
    __bf16* gwlo  = (__bf16*)(ws + alloc(10 * 8 * 64 * 8 * 2));
    float* featT  = (float*)(ws + alloc((size_t)BB * NN * CC * 4));
    bf16*  hstore = (bf16*)(ws + alloc((size_t)BB * E * PH * 2));
    float* Ssum   = (float*)(ws + alloc(BB * PH * 4));
    float* S2sum  = (float*)(ws + alloc(BB * PH * 4));
    int*   cnt    = (int*)(ws + alloc(BB * NN * 4));
    int*   ecol   = (int*)(ws + alloc((size_t)BB * NN * ELLW * 4));
    float* eval_  = (float*)(ws + alloc((size_t)BB * NN * ELLW * 4));
    float* g1     = (float*)(ws + alloc((size_t)BB * NN * GH * 4));
    float* g2     = (float*)(ws + alloc(BB * NN * 4));
    (void)ws_size; (void)n_in; (void)out_size;

    k_prep<<<dim3(160), dim3(256), 0, stream>>>(w1, gc1w, whi, wlo, gwhi, gwlo,
                                                cnt, Ssum, S2sum);
    k_transpose<<<dim3(BB * 320), dim3(256), 0, stream>>>(search, xcorr, featT);
    k_edge<<<dim3(nNG + BB * nbKP), dim3(512), 0, stream>>>(featT, pairs,
                                                            (const uint4*)whi, b1,
                                                            hstore, Ssum, S2sum,
                                                            E, EKP, nNG);
    k_edge_val<<<dim3(BB * nb), dim3(256), 0, stream>>>(hstore, Ssum, S2sum,
                                                        gamma, beta, w2, b2,
                                                        pairs, cnt, ecol, eval_, E);
    k_gc1<<<dim3(BB * 32), dim3(256), 0, stream>>>(featT, gwhi, gwlo, g1);
    k_spmm1<<<dim3(BB * NN), dim3(64), 0, stream>>>(g1, cnt, ecol, eval_, gc2w, g2);
    k_spmm2<<<dim3(BB * NN), dim3(64), 0, stream>>>(g2, cnt, ecol, eval_, out);
}